// Round 10
// baseline (5156.336 us; speedup 1.0000x reference)
//
#include <hip/hip_runtime.h>
#include <math.h>
#include <stdint.h>

// AIS estimator: N=1024 samples, B=128, DIM=DX=64, K=16 anneal steps, 3 leapfrog.
// Round 10: eigenbasis decoupling. A = V Lam V^T (device Jacobi in setup);
// z = y V makes the leapfrog DIAGONAL -> the 3 per-substep 64x64 matvecs
// vanish. Only 1 matvec/step remains: pz = p V (p drawn bit-exact in the
// original basis by JAX-threefry; basis rotation is the only way to keep RNG
// bit-exactness). w = fz.z - 0.5 z.Lam.z + wc with fz = f V precomputed.
// Proven r9 invariants kept: named-float4 state only, rolled `unroll 4`
// matvec, __launch_bounds__(256,2) (VGPR cap 128; cap=256/min_waves law).

#define WS_A     0
#define WS_MU    4096
#define WS_C     12288
#define WS_XSQ   20480
#define WS_AMU   20608
#define WS_F     28800
#define WS_WC    36992
#define WS_V     37120
#define WS_LAM   41216
#define WS_FZ    41280
#define WS_SLW   49472
#define WS_TOTAL (WS_SLW + 131072)

#define LOG2PI 1.8378770664093453f

struct KParams {
  float beta[18];
  float dbeta[17];
  uint32_t fk0[16];
  uint32_t fk1[16];
};

__host__ __device__ static inline void threefry2x32(uint32_t ks0, uint32_t ks1,
                                                    uint32_t x0, uint32_t x1,
                                                    uint32_t& o0, uint32_t& o1) {
  uint32_t ks2 = ks0 ^ ks1 ^ 0x1BD11BDAu;
  x0 += ks0; x1 += ks1;
#define TFR(r) { x0 += x1; x1 = (x1 << (r)) | (x1 >> (32 - (r))); x1 ^= x0; }
  TFR(13) TFR(15) TFR(26) TFR(6)
  x0 += ks1; x1 += ks2 + 1u;
  TFR(17) TFR(29) TFR(16) TFR(24)
  x0 += ks2; x1 += ks0 + 2u;
  TFR(13) TFR(15) TFR(26) TFR(6)
  x0 += ks0; x1 += ks1 + 3u;
  TFR(17) TFR(29) TFR(16) TFR(24)
  x0 += ks1; x1 += ks2 + 4u;
  TFR(13) TFR(15) TFR(26) TFR(6)
  x0 += ks2; x1 += ks0 + 5u;
#undef TFR
  o0 = x0; o1 = x1;
}

__device__ __forceinline__ float u_from_bits(uint32_t bits) {
  const float LO = __uint_as_float(0xBF7FFFFFu);  // nextafter(-1,0) in f32
  float f = __uint_as_float((bits >> 9) | 0x3F800000u) - 1.0f;
  float u = fmaf(f, 2.0f, LO);
  return fmaxf(LO, u);
}

// XLA ErfInv32 (Giles)
__device__ __forceinline__ float erfinv_f(float x) {
  float w = -log1pf(-x * x);
  float p;
  if (w < 5.0f) {
    w -= 2.5f;
    p = 2.81022636e-08f;
    p = fmaf(p, w, 3.43273939e-07f);
    p = fmaf(p, w, -3.5233877e-06f);
    p = fmaf(p, w, -4.39150654e-06f);
    p = fmaf(p, w, 0.00021858087f);
    p = fmaf(p, w, -0.00125372503f);
    p = fmaf(p, w, -0.00417768164f);
    p = fmaf(p, w, 0.246640727f);
    p = fmaf(p, w, 1.50140941f);
  } else {
    w = sqrtf(w) - 3.0f;
    p = -0.000200214257f;
    p = fmaf(p, w, 0.000100950558f);
    p = fmaf(p, w, 0.00134934322f);
    p = fmaf(p, w, -0.00367342844f);
    p = fmaf(p, w, 0.00573950773f);
    p = fmaf(p, w, -0.0076224613f);
    p = fmaf(p, w, 0.00943887047f);
    p = fmaf(p, w, 1.00167406f);
    p = fmaf(p, w, 2.83297682f);
  }
  return p * x;
}

// ---- setup1: A = Wdec Wdec^T ; mu[b][d] ; c[b][d] ; xsq[b]
__global__ void k_setup1(const float* __restrict__ x, const float* __restrict__ Wenc,
                         const float* __restrict__ Wdec, float* __restrict__ ws) {
  int t = blockIdx.x * 256 + threadIdx.x;
  if (t < 4096) {
    int i = t >> 6, j = t & 63;
    float s = 0;
    for (int e = 0; e < 64; ++e) s = fmaf(Wdec[i*64+e], Wdec[j*64+e], s);
    ws[WS_A + t] = s;
  } else if (t < 12288) {
    int u = t - 4096; int b = u >> 6, d = u & 63;
    float s = 0;
    for (int e = 0; e < 64; ++e) s = fmaf(x[b*64+e], Wenc[e*64+d], s);
    ws[WS_MU + u] = s;
  } else if (t < 20480) {
    int u = t - 12288; int b = u >> 6, d = u & 63;
    float s = 0;
    for (int e = 0; e < 64; ++e) s = fmaf(x[b*64+e], Wdec[d*64+e], s);
    ws[WS_C + u] = s;
  } else if (t < 20608) {
    int b = t - 20480;
    float s = 0;
    for (int e = 0; e < 64; ++e) s = fmaf(x[b*64+e], x[b*64+e], s);
    ws[WS_XSQ + b] = s;
  }
}

// ---- k_eig: cyclic Jacobi (tournament parallel, 32 disjoint pairs/round),
// 8 sweeps x 63 rounds. A <- J^T A J, V <- V J. One block of 256 threads.
__global__ void k_eig(float* __restrict__ ws) {
  __shared__ float Am[4096];
  __shared__ float Vm[4096];
  __shared__ float cs_c[32], cs_s[32];
  __shared__ int pu[32], pv[32];
  const int tid = threadIdx.x;
  for (int i = tid; i < 4096; i += 256) {
    Am[i] = ws[WS_A + i];
    Vm[i] = ((i >> 6) == (i & 63)) ? 1.0f : 0.0f;
  }
  __syncthreads();
  for (int sweep = 0; sweep < 8; ++sweep) {
    for (int r = 0; r < 63; ++r) {
      if (tid < 32) {
        int j = tid;
        int u, v;
        if (j == 0) { u = 0; v = 1 + ((62 + r) % 63); }
        else { u = 1 + ((j - 1 + r) % 63); v = 1 + ((62 - j + r) % 63); }
        float app = Am[u*64+u], aqq = Am[v*64+v], apq = Am[u*64+v];
        float c = 1.0f, s = 0.0f;
        if (fabsf(apq) > 1e-30f) {
          float tau = (aqq - app) / (2.0f * apq);
          float t = copysignf(1.0f / (fabsf(tau) + sqrtf(fmaf(tau, tau, 1.0f))), tau);
          c = 1.0f / sqrtf(fmaf(t, t, 1.0f));
          s = t * c;
        }
        pu[j] = u; pv[j] = v; cs_c[j] = c; cs_s[j] = s;
      }
      __syncthreads();
      // rows: A <- J^T A  (pairs disjoint -> parallel-safe)
      for (int it = 0; it < 8; ++it) {
        int idx = tid + it*256;
        int j = idx >> 6, k = idx & 63;
        int u = pu[j], v = pv[j];
        float c = cs_c[j], s = cs_s[j];
        float au = Am[u*64+k], av = Am[v*64+k];
        Am[u*64+k] = c*au - s*av;
        Am[v*64+k] = fmaf(s, au, c*av);
      }
      __syncthreads();
      // cols: A <- A J ; V <- V J
      for (int it = 0; it < 8; ++it) {
        int idx = tid + it*256;
        int j = idx >> 6, k = idx & 63;
        int u = pu[j], v = pv[j];
        float c = cs_c[j], s = cs_s[j];
        float au = Am[k*64+u], av = Am[k*64+v];
        Am[k*64+u] = c*au - s*av;
        Am[k*64+v] = fmaf(s, au, c*av);
        float vu = Vm[k*64+u], vv = Vm[k*64+v];
        Vm[k*64+u] = c*vu - s*vv;
        Vm[k*64+v] = fmaf(s, vu, c*vv);
      }
      __syncthreads();
    }
  }
  for (int i = tid; i < 4096; i += 256) ws[WS_V + i] = Vm[i];
  if (tid < 64) ws[WS_LAM + tid] = Am[tid*64 + tid];
}

// ---- setup2: amu[b][d] = (mu A)[d] ; f[b][d] = c - mu - amu
__global__ void k_setup2(float* __restrict__ ws) {
  int t = blockIdx.x * 256 + threadIdx.x;
  if (t < 8192) {
    int b = t >> 6, d = t & 63;
    float s = 0;
    for (int m = 0; m < 64; ++m) s = fmaf(ws[WS_MU + b*64+m], ws[WS_A + m*64+d], s);
    ws[WS_AMU + t] = s;
    ws[WS_F + t] = ws[WS_C + t] - ws[WS_MU + t] - s;
  }
}

// ---- setup3: wconst[b]
__global__ void k_setup3(float* __restrict__ ws) {
  int b = threadIdx.x;
  if (b < 128) {
    float muc = 0, musq = 0, muamu = 0;
    for (int d = 0; d < 64; ++d) {
      float m = ws[WS_MU + b*64+d];
      muc   = fmaf(m, ws[WS_C + b*64+d], muc);
      musq  = fmaf(m, m, musq);
      muamu = fmaf(m, ws[WS_AMU + b*64+d], muamu);
    }
    ws[WS_WC + b] = -32.0f * LOG2PI - 0.5f * ws[WS_XSQ + b]
                    + muc - 0.5f * musq - 0.5f * muamu;
  }
}

// ---- setup4: fz[b][d] = sum_m f[b][m] V[m][d]
__global__ void k_setupfz(float* __restrict__ ws) {
  int t = blockIdx.x * 256 + threadIdx.x;
  if (t < 8192) {
    int b = t >> 6, d = t & 63;
    float s = 0;
    for (int m = 0; m < 64; ++m) s = fmaf(ws[WS_F + b*64+m], ws[WS_V + m*64+d], s);
    ws[WS_FZ + t] = s;
  }
}

// ---- hot-loop macros: scalar/float4 only, nothing address-taken -----------

#define MVROW(QS, RP, T0, T1, T2, T3)                                        \
  {                                                                          \
    float4 a0v = *(const float4*)((RP) + 0);                                 \
    float4 a1v = *(const float4*)((RP) + 4);                                 \
    float4 a2v = *(const float4*)((RP) + 8);                                 \
    float4 a3v = *(const float4*)((RP) + 12);                                \
    T0.x = fmaf(QS, a0v.x, T0.x); T0.y = fmaf(QS, a0v.y, T0.y);              \
    T0.z = fmaf(QS, a0v.z, T0.z); T0.w = fmaf(QS, a0v.w, T0.w);              \
    T1.x = fmaf(QS, a1v.x, T1.x); T1.y = fmaf(QS, a1v.y, T1.y);              \
    T1.z = fmaf(QS, a1v.z, T1.z); T1.w = fmaf(QS, a1v.w, T1.w);              \
    T2.x = fmaf(QS, a2v.x, T2.x); T2.y = fmaf(QS, a2v.y, T2.y);              \
    T2.z = fmaf(QS, a2v.z, T2.z); T2.w = fmaf(QS, a2v.w, T2.w);              \
    T3.x = fmaf(QS, a3v.x, T3.x); T3.y = fmaf(QS, a3v.y, T3.y);              \
    T3.z = fmaf(QS, a3v.z, T3.z); T3.w = fmaf(QS, a3v.w, T3.w);              \
  }

// (T0..T3) = (vec_in_pls_row . V)[d0..d0+16): rolled `unroll 4` loop (the only
// body shape that hasn't triggered scheduler spill-explosion; r6/r9 evidence)
#define MATVEC_V(T0, T1, T2, T3)                                             \
  T0 = make_float4(0.f, 0.f, 0.f, 0.f); T1 = T0; T2 = T0; T3 = T0;           \
  _Pragma("unroll 4")                                                        \
  for (int m4 = 0; m4 < 16; ++m4) {                                          \
    float4 q4 = *(const float4*)(pme + 4 * m4);                              \
    const float* rp = Vs + m4 * 256 + d0;                                    \
    MVROW(q4.x, rp,       T0, T1, T2, T3)                                    \
    MVROW(q4.y, rp + 64,  T0, T1, T2, T3)                                    \
    MVROW(q4.z, rp + 128, T0, T1, T2, T3)                                    \
    MVROW(q4.w, rp + 192, T0, T1, T2, T3)                                    \
  }

#define EBF1(EC, BC, LC, FC) EC = fmaf(bk, LC, 1.0f); BC = bk * FC;
#define EBF4(EV, BV, LV, FV)                                                 \
  EBF1(EV.x, BV.x, LV.x, FV.x) EBF1(EV.y, BV.y, LV.y, FV.y)                  \
  EBF1(EV.z, BV.z, LV.z, FV.z) EBF1(EV.w, BV.w, LV.w, FV.w)

// diagonal leapfrog substep: kick(h/2 or doubled) + drift, per component
#define LF1(ZC, PC, EC, BC, DBL)                                             \
  { float g = fmaf(-(EC), ZC, BC);                                           \
    PC = fmaf(0.025f, g, PC);                                                \
    if (DBL) PC = fmaf(0.025f, g, PC);                                       \
    ZC = fmaf(0.05f, PC, ZC); }
#define LF4(ZV, PV, EV, BV, DBL)                                             \
  LF1(ZV.x, PV.x, EV.x, BV.x, DBL) LF1(ZV.y, PV.y, EV.y, BV.y, DBL)          \
  LF1(ZV.z, PV.z, EV.z, BV.z, DBL) LF1(ZV.w, PV.w, EV.w, BV.w, DBL)
#define SUBSTEP(DBL)                                                         \
  LF4(z0, pz0, e0, bf0, DBL) LF4(z1, pz1, e1, bf1, DBL)                      \
  LF4(z2, pz2, e2, bf2, DBL) LF4(z3, pz3, e3, bf3, DBL)

#define WDOT4(S1, S2, FV, ZV, LV)                                            \
  { float t0 = LV.x * ZV.x; S2 = fmaf(t0, ZV.x, S2); S1 = fmaf(FV.x, ZV.x, S1); \
    float t1 = LV.y * ZV.y; S2 = fmaf(t1, ZV.y, S2); S1 = fmaf(FV.y, ZV.y, S1); \
    float t2 = LV.z * ZV.z; S2 = fmaf(t2, ZV.z, S2); S1 = fmaf(FV.z, ZV.z, S1); \
    float t3 = LV.w * ZV.w; S2 = fmaf(t3, ZV.w, S2); S1 = fmaf(FV.w, ZV.w, S1); }

#define W_EVAL(WOUT)                                                         \
  {                                                                          \
    float s1 = 0.f, s2 = 0.f;                                                \
    WDOT4(s1, s2, fz0, z0, lm0) WDOT4(s1, s2, fz1, z1, lm1)                  \
    WDOT4(s1, s2, fz2, z2, lm2) WDOT4(s1, s2, fz3, z3, lm3)                  \
    float v = fmaf(-0.5f, s2, s1);                                           \
    v += __shfl_xor(v, 1);                                                   \
    v += __shfl_xor(v, 2);                                                   \
    WOUT = v + wc;                                                           \
  }

#define DRAW(PC, IDX)                                                        \
  { uint32_t o0, o1;                                                         \
    threefry2x32(k0, k1, 0u, base + (IDX), o0, o1);                          \
    PC = 1.41421356f * erfinv_f(u_from_bits(o0 ^ o1)); }

#define STORE_P(A0, A1, A2, A3)                                              \
  *(float4*)(pme + d0 +  0) = A0; *(float4*)(pme + d0 +  4) = A1;            \
  *(float4*)(pme + d0 +  8) = A2; *(float4*)(pme + d0 + 12) = A3;

// ---- main: 4 lanes per trajectory (16 dims each), 64 trajectories/block
__global__ __launch_bounds__(256, 2) void k_main(const float* __restrict__ qn,
                                                 const float* __restrict__ ws,
                                                 float* __restrict__ slw_out,
                                                 KParams P) {
  __shared__ float Vs[4096];
  __shared__ float pls[64 * 68];  // [traj][dim], pad 68: float4 rows, 2-way bank
  const int tid = threadIdx.x;
  for (int i = tid; i < 4096; i += 256) Vs[i] = ws[WS_V + i];
  __syncthreads();

  const int ltraj = tid >> 2, sub = tid & 3;
  const int gtraj = blockIdx.x * 64 + ltraj;
  const int b = gtraj & 127;
  const int d0 = sub * 16;
  float* pme = pls + ltraj * 68;
  const float wc = ws[WS_WC + b];

  float4 fz0, fz1, fz2, fz3, lm0, lm1, lm2, lm3;
  {
    const float4* fzP = (const float4*)(ws + WS_FZ + b*64 + d0);
    fz0 = fzP[0]; fz1 = fzP[1]; fz2 = fzP[2]; fz3 = fzP[3];
    const float4* lmP = (const float4*)(ws + WS_LAM + d0);
    lm0 = lmP[0]; lm1 = lmP[1]; lm2 = lmP[2]; lm3 = lmP[3];
  }

  float4 z0, z1, z2, z3, pz0, pz1, pz2, pz3;
  float slw = 0.0f;

  // j = 0: y0 = q_noise (y-domain) -> z0 = qn . V
  {
    const float4* qn4 = (const float4*)(qn + (size_t)gtraj*64 + d0);
    float4 a0 = qn4[0], a1 = qn4[1], a2 = qn4[2], a3 = qn4[3];
    STORE_P(a0, a1, a2, a3)
  }
  MATVEC_V(z0, z1, z2, z3)
  {
    float w0;
    W_EVAL(w0);
    slw = fmaf(P.dbeta[0], w0, slw);
  }

  const uint32_t base = (uint32_t)gtraj * 64u + (uint32_t)d0;
  for (int j = 1; j <= 16; ++j) {
    const float bk = P.beta[j];
    const uint32_t k0 = P.fk0[j-1], k1 = P.fk1[j-1];
    // momentum refresh (original basis, bit-exact), staged to LDS for rotation
    {
      float4 a0, a1, a2, a3;
      DRAW(a0.x,  0u) DRAW(a0.y,  1u) DRAW(a0.z,  2u) DRAW(a0.w,  3u)
      DRAW(a1.x,  4u) DRAW(a1.y,  5u) DRAW(a1.z,  6u) DRAW(a1.w,  7u)
      DRAW(a2.x,  8u) DRAW(a2.y,  9u) DRAW(a2.z, 10u) DRAW(a2.w, 11u)
      DRAW(a3.x, 12u) DRAW(a3.y, 13u) DRAW(a3.z, 14u) DRAW(a3.w, 15u)
      STORE_P(a0, a1, a2, a3)
    }
    MATVEC_V(pz0, pz1, pz2, pz3)          // pz = p . V
    float4 e0, e1, e2, e3, bf0, bf1, bf2, bf3;
    EBF4(e0, bf0, lm0, fz0) EBF4(e1, bf1, lm1, fz1)
    EBF4(e2, bf2, lm2, fz2) EBF4(e3, bf3, lm3, fz3)
    SUBSTEP(false)
    SUBSTEP(true)
    SUBSTEP(true)
    float wj;
    W_EVAL(wj);
    slw = fmaf(P.dbeta[j], wj, slw);
  }
  if (sub == 0) slw_out[gtraj] = slw;
}

// ---- logsumexp over n per batch column b
__global__ void k_reduce(const float* __restrict__ slw, float* __restrict__ out) {
  __shared__ float red[256];
  int b = blockIdx.x, t = threadIdx.x;
  float v0 = slw[t*128 + b];
  float v1 = slw[(t+256)*128 + b];
  float v2 = slw[(t+512)*128 + b];
  float v3 = slw[(t+768)*128 + b];
  float m = fmaxf(fmaxf(v0, v1), fmaxf(v2, v3));
  red[t] = m; __syncthreads();
  for (int s = 128; s > 0; s >>= 1) {
    if (t < s) red[t] = fmaxf(red[t], red[t+s]);
    __syncthreads();
  }
  m = red[0]; __syncthreads();
  float sum = expf(v0 - m) + expf(v1 - m) + expf(v2 - m) + expf(v3 - m);
  red[t] = sum; __syncthreads();
  for (int s = 128; s > 0; s >>= 1) {
    if (t < s) red[t] += red[t+s];
    __syncthreads();
  }
  if (t == 0) out[b] = m + logf(red[0]) - 6.93147180559945309f;  // - log(1024)
}

extern "C" void kernel_launch(void* const* d_in, const int* in_sizes, int n_in,
                              void* d_out, int out_size, void* d_ws, size_t ws_size,
                              hipStream_t stream) {
  const float* x    = (const float*)d_in[0];
  const float* Wenc = (const float*)d_in[1];
  const float* Wdec = (const float*)d_in[2];
  const float* qn   = (const float*)d_in[3];
  // d_in[4] (p_noise) is dead: momentum fully resampled every anneal step.
  float* ws  = (float*)d_ws;
  float* out = (float*)d_out;
  if (ws_size < (size_t)WS_TOTAL * sizeof(float)) return;

  KParams P;
  double bb[18];
  for (int i = 0; i < 18; ++i) {
    double tt = (double)i / 17.0;
    bb[i] = 1.0 / (1.0 + exp(-(8.0 * tt - 4.0)));
  }
  for (int i = 0; i < 18; ++i) P.beta[i] = (float)((bb[i] - bb[0]) / (bb[17] - bb[0]));
  for (int j = 0; j <= 16; ++j) P.dbeta[j] = P.beta[j+1] - P.beta[j];
  for (int k = 1; k <= 16; ++k) {
    uint32_t a, c;
    threefry2x32(0u, 42u, 0u, (uint32_t)k, a, c);  // fold_in(key(42), k)
    P.fk0[k-1] = a; P.fk1[k-1] = c;
  }

  hipLaunchKernelGGL(k_setup1, dim3(81), dim3(256), 0, stream, x, Wenc, Wdec, ws);
  hipLaunchKernelGGL(k_eig, dim3(1), dim3(256), 0, stream, ws);
  hipLaunchKernelGGL(k_setup2, dim3(32), dim3(256), 0, stream, ws);
  hipLaunchKernelGGL(k_setup3, dim3(1), dim3(128), 0, stream, ws);
  hipLaunchKernelGGL(k_setupfz, dim3(32), dim3(256), 0, stream, ws);
  hipLaunchKernelGGL(k_main, dim3(2048), dim3(256), 0, stream, qn, ws, ws + WS_SLW, P);
  hipLaunchKernelGGL(k_reduce, dim3(128), dim3(256), 0, stream, ws + WS_SLW, out);
}

// Round 11
// 1257.042 us; speedup vs baseline: 4.1020x; 4.1020x over previous
//
#include <hip/hip_runtime.h>
#include <math.h>
#include <stdint.h>

// AIS estimator: N=1024 samples, B=128, DIM=DX=64, K=16 anneal steps, 3 leapfrog.
// Round 11: r10 eigen-decoupled structure with the k_eig bank-conflict fix.
//  - k_eig LDS pitch 64 -> 65: column updates Am[k*64+u] were 64-way bank
//    conflicts (8e6 conflict-cycles, 6.6us/round, 4ms total on 1 CU).
//    Pitch 65 -> bank (k+u)%32 = 2-way = free. Sweeps 8 -> 5 (quadratic
//    convergence; off-diag ~1e-8 rel, tolerance 3.7 abs).
//  - k_main: __launch_bounds__(256,3) (cap 84 >= 68 used; r4-r8 law
//    cap=256/min_waves) -> 3 waves/SIMD to hide threefry dep-chain stalls.
//  - erfinv: -log1p(-x^2) -> -__logf(fma(-x,x,1)): ~10 inst/draw cheaper,
//    ~1e-7 abs normals delta (slack established: r10 absmax 0.0).
//  - All else identical to r10 (absmax 0.0): diagonal leapfrog in z = y V,
//    1 matvec/step (pz = p V, bit-exact JAX partitionable threefry draws),
//    named-float4 state, rolled `unroll 4` matvec.

#define WS_A     0
#define WS_MU    4096
#define WS_C     12288
#define WS_XSQ   20480
#define WS_AMU   20608
#define WS_F     28800
#define WS_WC    36992
#define WS_V     37120
#define WS_LAM   41216
#define WS_FZ    41280
#define WS_SLW   49472
#define WS_TOTAL (WS_SLW + 131072)

#define LOG2PI 1.8378770664093453f

struct KParams {
  float beta[18];
  float dbeta[17];
  uint32_t fk0[16];
  uint32_t fk1[16];
};

__host__ __device__ static inline void threefry2x32(uint32_t ks0, uint32_t ks1,
                                                    uint32_t x0, uint32_t x1,
                                                    uint32_t& o0, uint32_t& o1) {
  uint32_t ks2 = ks0 ^ ks1 ^ 0x1BD11BDAu;
  x0 += ks0; x1 += ks1;
#define TFR(r) { x0 += x1; x1 = (x1 << (r)) | (x1 >> (32 - (r))); x1 ^= x0; }
  TFR(13) TFR(15) TFR(26) TFR(6)
  x0 += ks1; x1 += ks2 + 1u;
  TFR(17) TFR(29) TFR(16) TFR(24)
  x0 += ks2; x1 += ks0 + 2u;
  TFR(13) TFR(15) TFR(26) TFR(6)
  x0 += ks0; x1 += ks1 + 3u;
  TFR(17) TFR(29) TFR(16) TFR(24)
  x0 += ks1; x1 += ks2 + 4u;
  TFR(13) TFR(15) TFR(26) TFR(6)
  x0 += ks2; x1 += ks0 + 5u;
#undef TFR
  o0 = x0; o1 = x1;
}

__device__ __forceinline__ float u_from_bits(uint32_t bits) {
  const float LO = __uint_as_float(0xBF7FFFFFu);  // nextafter(-1,0) in f32
  float f = __uint_as_float((bits >> 9) | 0x3F800000u) - 1.0f;
  float u = fmaf(f, 2.0f, LO);
  return fmaxf(LO, u);
}

// XLA ErfInv32 (Giles); log1p(-x^2) replaced by __logf(1-x^2) (fast native,
// ~1e-7 abs delta on the output normal — inside tolerance slack).
__device__ __forceinline__ float erfinv_f(float x) {
  float w = -__logf(fmaf(-x, x, 1.0f));
  float p;
  if (w < 5.0f) {
    w -= 2.5f;
    p = 2.81022636e-08f;
    p = fmaf(p, w, 3.43273939e-07f);
    p = fmaf(p, w, -3.5233877e-06f);
    p = fmaf(p, w, -4.39150654e-06f);
    p = fmaf(p, w, 0.00021858087f);
    p = fmaf(p, w, -0.00125372503f);
    p = fmaf(p, w, -0.00417768164f);
    p = fmaf(p, w, 0.246640727f);
    p = fmaf(p, w, 1.50140941f);
  } else {
    w = sqrtf(w) - 3.0f;
    p = -0.000200214257f;
    p = fmaf(p, w, 0.000100950558f);
    p = fmaf(p, w, 0.00134934322f);
    p = fmaf(p, w, -0.00367342844f);
    p = fmaf(p, w, 0.00573950773f);
    p = fmaf(p, w, -0.0076224613f);
    p = fmaf(p, w, 0.00943887047f);
    p = fmaf(p, w, 1.00167406f);
    p = fmaf(p, w, 2.83297682f);
  }
  return p * x;
}

// ---- setup1: A = Wdec Wdec^T ; mu[b][d] ; c[b][d] ; xsq[b]
__global__ void k_setup1(const float* __restrict__ x, const float* __restrict__ Wenc,
                         const float* __restrict__ Wdec, float* __restrict__ ws) {
  int t = blockIdx.x * 256 + threadIdx.x;
  if (t < 4096) {
    int i = t >> 6, j = t & 63;
    float s = 0;
    for (int e = 0; e < 64; ++e) s = fmaf(Wdec[i*64+e], Wdec[j*64+e], s);
    ws[WS_A + t] = s;
  } else if (t < 12288) {
    int u = t - 4096; int b = u >> 6, d = u & 63;
    float s = 0;
    for (int e = 0; e < 64; ++e) s = fmaf(x[b*64+e], Wenc[e*64+d], s);
    ws[WS_MU + u] = s;
  } else if (t < 20480) {
    int u = t - 12288; int b = u >> 6, d = u & 63;
    float s = 0;
    for (int e = 0; e < 64; ++e) s = fmaf(x[b*64+e], Wdec[d*64+e], s);
    ws[WS_C + u] = s;
  } else if (t < 20608) {
    int b = t - 20480;
    float s = 0;
    for (int e = 0; e < 64; ++e) s = fmaf(x[b*64+e], x[b*64+e], s);
    ws[WS_XSQ + b] = s;
  }
}

// ---- k_eig: cyclic Jacobi (tournament, 32 disjoint pairs/round), 5 sweeps
// x 63 rounds. LDS pitch 65: col accesses stride-65 -> bank (k+u)%32, 2-way
// (free). (Pitch 64 was a 64-way conflict: 8e6 conflict-cycles, 4 ms.)
#define EP 65
__global__ void k_eig(float* __restrict__ ws) {
  __shared__ float Am[64 * EP];
  __shared__ float Vm[64 * EP];
  __shared__ float cs_c[32], cs_s[32];
  __shared__ int pu[32], pv[32];
  const int tid = threadIdx.x;
  for (int i = tid; i < 4096; i += 256) {
    int r = i >> 6, c = i & 63;
    Am[r*EP + c] = ws[WS_A + i];
    Vm[r*EP + c] = (r == c) ? 1.0f : 0.0f;
  }
  __syncthreads();
  for (int sweep = 0; sweep < 5; ++sweep) {
    for (int r = 0; r < 63; ++r) {
      if (tid < 32) {
        int j = tid;
        int u, v;
        if (j == 0) { u = 0; v = 1 + ((62 + r) % 63); }
        else { u = 1 + ((j - 1 + r) % 63); v = 1 + ((62 - j + r) % 63); }
        float app = Am[u*(EP+1)], aqq = Am[v*(EP+1)], apq = Am[u*EP+v];
        float c = 1.0f, s = 0.0f;
        if (fabsf(apq) > 1e-30f) {
          float tau = (aqq - app) / (2.0f * apq);
          float t = copysignf(1.0f / (fabsf(tau) + sqrtf(fmaf(tau, tau, 1.0f))), tau);
          c = 1.0f / sqrtf(fmaf(t, t, 1.0f));
          s = t * c;
        }
        pu[j] = u; pv[j] = v; cs_c[j] = c; cs_s[j] = s;
      }
      __syncthreads();
      // rows: A <- J^T A  (stride-1 across lanes, conflict-free)
      for (int it = 0; it < 8; ++it) {
        int idx = tid + it*256;
        int j = idx >> 6, k = idx & 63;
        int u = pu[j], v = pv[j];
        float c = cs_c[j], s = cs_s[j];
        float au = Am[u*EP+k], av = Am[v*EP+k];
        Am[u*EP+k] = c*au - s*av;
        Am[v*EP+k] = fmaf(s, au, c*av);
      }
      __syncthreads();
      // cols: A <- A J ; V <- V J  (stride-65 across lanes -> 2-way, free)
      for (int it = 0; it < 8; ++it) {
        int idx = tid + it*256;
        int j = idx >> 6, k = idx & 63;
        int u = pu[j], v = pv[j];
        float c = cs_c[j], s = cs_s[j];
        float au = Am[k*EP+u], av = Am[k*EP+v];
        Am[k*EP+u] = c*au - s*av;
        Am[k*EP+v] = fmaf(s, au, c*av);
        float vu = Vm[k*EP+u], vv = Vm[k*EP+v];
        Vm[k*EP+u] = c*vu - s*vv;
        Vm[k*EP+v] = fmaf(s, vu, c*vv);
      }
      __syncthreads();
    }
  }
  for (int i = tid; i < 4096; i += 256) ws[WS_V + i] = Vm[(i >> 6)*EP + (i & 63)];
  if (tid < 64) ws[WS_LAM + tid] = Am[tid*(EP+1)];
}

// ---- setup2: amu[b][d] = (mu A)[d] ; f[b][d] = c - mu - amu
__global__ void k_setup2(float* __restrict__ ws) {
  int t = blockIdx.x * 256 + threadIdx.x;
  if (t < 8192) {
    int b = t >> 6, d = t & 63;
    float s = 0;
    for (int m = 0; m < 64; ++m) s = fmaf(ws[WS_MU + b*64+m], ws[WS_A + m*64+d], s);
    ws[WS_AMU + t] = s;
    ws[WS_F + t] = ws[WS_C + t] - ws[WS_MU + t] - s;
  }
}

// ---- setup3: wconst[b]
__global__ void k_setup3(float* __restrict__ ws) {
  int b = threadIdx.x;
  if (b < 128) {
    float muc = 0, musq = 0, muamu = 0;
    for (int d = 0; d < 64; ++d) {
      float m = ws[WS_MU + b*64+d];
      muc   = fmaf(m, ws[WS_C + b*64+d], muc);
      musq  = fmaf(m, m, musq);
      muamu = fmaf(m, ws[WS_AMU + b*64+d], muamu);
    }
    ws[WS_WC + b] = -32.0f * LOG2PI - 0.5f * ws[WS_XSQ + b]
                    + muc - 0.5f * musq - 0.5f * muamu;
  }
}

// ---- setup4: fz[b][d] = sum_m f[b][m] V[m][d]
__global__ void k_setupfz(float* __restrict__ ws) {
  int t = blockIdx.x * 256 + threadIdx.x;
  if (t < 8192) {
    int b = t >> 6, d = t & 63;
    float s = 0;
    for (int m = 0; m < 64; ++m) s = fmaf(ws[WS_F + b*64+m], ws[WS_V + m*64+d], s);
    ws[WS_FZ + t] = s;
  }
}

// ---- hot-loop macros: scalar/float4 only, nothing address-taken -----------

#define MVROW(QS, RP, T0, T1, T2, T3)                                        \
  {                                                                          \
    float4 a0v = *(const float4*)((RP) + 0);                                 \
    float4 a1v = *(const float4*)((RP) + 4);                                 \
    float4 a2v = *(const float4*)((RP) + 8);                                 \
    float4 a3v = *(const float4*)((RP) + 12);                                \
    T0.x = fmaf(QS, a0v.x, T0.x); T0.y = fmaf(QS, a0v.y, T0.y);              \
    T0.z = fmaf(QS, a0v.z, T0.z); T0.w = fmaf(QS, a0v.w, T0.w);              \
    T1.x = fmaf(QS, a1v.x, T1.x); T1.y = fmaf(QS, a1v.y, T1.y);              \
    T1.z = fmaf(QS, a1v.z, T1.z); T1.w = fmaf(QS, a1v.w, T1.w);              \
    T2.x = fmaf(QS, a2v.x, T2.x); T2.y = fmaf(QS, a2v.y, T2.y);              \
    T2.z = fmaf(QS, a2v.z, T2.z); T2.w = fmaf(QS, a2v.w, T2.w);              \
    T3.x = fmaf(QS, a3v.x, T3.x); T3.y = fmaf(QS, a3v.y, T3.y);              \
    T3.z = fmaf(QS, a3v.z, T3.z); T3.w = fmaf(QS, a3v.w, T3.w);              \
  }

#define MATVEC_V(T0, T1, T2, T3)                                             \
  T0 = make_float4(0.f, 0.f, 0.f, 0.f); T1 = T0; T2 = T0; T3 = T0;           \
  _Pragma("unroll 4")                                                        \
  for (int m4 = 0; m4 < 16; ++m4) {                                          \
    float4 q4 = *(const float4*)(pme + 4 * m4);                              \
    const float* rp = Vs + m4 * 256 + d0;                                    \
    MVROW(q4.x, rp,       T0, T1, T2, T3)                                    \
    MVROW(q4.y, rp + 64,  T0, T1, T2, T3)                                    \
    MVROW(q4.z, rp + 128, T0, T1, T2, T3)                                    \
    MVROW(q4.w, rp + 192, T0, T1, T2, T3)                                    \
  }

#define EBF1(EC, BC, LC, FC) EC = fmaf(bk, LC, 1.0f); BC = bk * FC;
#define EBF4(EV, BV, LV, FV)                                                 \
  EBF1(EV.x, BV.x, LV.x, FV.x) EBF1(EV.y, BV.y, LV.y, FV.y)                  \
  EBF1(EV.z, BV.z, LV.z, FV.z) EBF1(EV.w, BV.w, LV.w, FV.w)

#define LF1(ZC, PC, EC, BC, DBL)                                             \
  { float g = fmaf(-(EC), ZC, BC);                                           \
    PC = fmaf(0.025f, g, PC);                                                \
    if (DBL) PC = fmaf(0.025f, g, PC);                                       \
    ZC = fmaf(0.05f, PC, ZC); }
#define LF4(ZV, PV, EV, BV, DBL)                                             \
  LF1(ZV.x, PV.x, EV.x, BV.x, DBL) LF1(ZV.y, PV.y, EV.y, BV.y, DBL)          \
  LF1(ZV.z, PV.z, EV.z, BV.z, DBL) LF1(ZV.w, PV.w, EV.w, BV.w, DBL)
#define SUBSTEP(DBL)                                                         \
  LF4(z0, pz0, e0, bf0, DBL) LF4(z1, pz1, e1, bf1, DBL)                      \
  LF4(z2, pz2, e2, bf2, DBL) LF4(z3, pz3, e3, bf3, DBL)

#define WDOT4(S1, S2, FV, ZV, LV)                                            \
  { float t0 = LV.x * ZV.x; S2 = fmaf(t0, ZV.x, S2); S1 = fmaf(FV.x, ZV.x, S1); \
    float t1 = LV.y * ZV.y; S2 = fmaf(t1, ZV.y, S2); S1 = fmaf(FV.y, ZV.y, S1); \
    float t2 = LV.z * ZV.z; S2 = fmaf(t2, ZV.z, S2); S1 = fmaf(FV.z, ZV.z, S1); \
    float t3 = LV.w * ZV.w; S2 = fmaf(t3, ZV.w, S2); S1 = fmaf(FV.w, ZV.w, S1); }

#define W_EVAL(WOUT)                                                         \
  {                                                                          \
    float s1 = 0.f, s2 = 0.f;                                                \
    WDOT4(s1, s2, fz0, z0, lm0) WDOT4(s1, s2, fz1, z1, lm1)                  \
    WDOT4(s1, s2, fz2, z2, lm2) WDOT4(s1, s2, fz3, z3, lm3)                  \
    float v = fmaf(-0.5f, s2, s1);                                           \
    v += __shfl_xor(v, 1);                                                   \
    v += __shfl_xor(v, 2);                                                   \
    WOUT = v + wc;                                                           \
  }

#define DRAW(PC, IDX)                                                        \
  { uint32_t o0, o1;                                                         \
    threefry2x32(k0, k1, 0u, base + (IDX), o0, o1);                          \
    PC = 1.41421356f * erfinv_f(u_from_bits(o0 ^ o1)); }

#define STORE_P(A0, A1, A2, A3)                                              \
  *(float4*)(pme + d0 +  0) = A0; *(float4*)(pme + d0 +  4) = A1;            \
  *(float4*)(pme + d0 +  8) = A2; *(float4*)(pme + d0 + 12) = A3;

// ---- main: 4 lanes per trajectory (16 dims each), 64 trajectories/block
// (256,3): VGPR cap 84 (r10 used 68 -> fits); 3 waves/SIMD to hide threefry
// dependency-chain stalls. LDS 33.8 KB x 3 = 101 KB < 160 OK.
__global__ __launch_bounds__(256, 3) void k_main(const float* __restrict__ qn,
                                                 const float* __restrict__ ws,
                                                 float* __restrict__ slw_out,
                                                 KParams P) {
  __shared__ float Vs[4096];
  __shared__ float pls[64 * 68];  // [traj][dim], pad 68: float4 rows, 2-way bank
  const int tid = threadIdx.x;
  for (int i = tid; i < 4096; i += 256) Vs[i] = ws[WS_V + i];
  __syncthreads();

  const int ltraj = tid >> 2, sub = tid & 3;
  const int gtraj = blockIdx.x * 64 + ltraj;
  const int b = gtraj & 127;
  const int d0 = sub * 16;
  float* pme = pls + ltraj * 68;
  const float wc = ws[WS_WC + b];

  float4 fz0, fz1, fz2, fz3, lm0, lm1, lm2, lm3;
  {
    const float4* fzP = (const float4*)(ws + WS_FZ + b*64 + d0);
    fz0 = fzP[0]; fz1 = fzP[1]; fz2 = fzP[2]; fz3 = fzP[3];
    const float4* lmP = (const float4*)(ws + WS_LAM + d0);
    lm0 = lmP[0]; lm1 = lmP[1]; lm2 = lmP[2]; lm3 = lmP[3];
  }

  float4 z0, z1, z2, z3, pz0, pz1, pz2, pz3;
  float slw = 0.0f;

  // j = 0: y0 = q_noise (y-domain) -> z0 = qn . V
  {
    const float4* qn4 = (const float4*)(qn + (size_t)gtraj*64 + d0);
    float4 a0 = qn4[0], a1 = qn4[1], a2 = qn4[2], a3 = qn4[3];
    STORE_P(a0, a1, a2, a3)
  }
  MATVEC_V(z0, z1, z2, z3)
  {
    float w0;
    W_EVAL(w0);
    slw = fmaf(P.dbeta[0], w0, slw);
  }

  const uint32_t base = (uint32_t)gtraj * 64u + (uint32_t)d0;
  for (int j = 1; j <= 16; ++j) {
    const float bk = P.beta[j];
    const uint32_t k0 = P.fk0[j-1], k1 = P.fk1[j-1];
    // momentum refresh (original basis, bit-exact), staged to LDS for rotation
    {
      float4 a0, a1, a2, a3;
      DRAW(a0.x,  0u) DRAW(a0.y,  1u) DRAW(a0.z,  2u) DRAW(a0.w,  3u)
      DRAW(a1.x,  4u) DRAW(a1.y,  5u) DRAW(a1.z,  6u) DRAW(a1.w,  7u)
      DRAW(a2.x,  8u) DRAW(a2.y,  9u) DRAW(a2.z, 10u) DRAW(a2.w, 11u)
      DRAW(a3.x, 12u) DRAW(a3.y, 13u) DRAW(a3.z, 14u) DRAW(a3.w, 15u)
      STORE_P(a0, a1, a2, a3)
    }
    MATVEC_V(pz0, pz1, pz2, pz3)          // pz = p . V
    float4 e0, e1, e2, e3, bf0, bf1, bf2, bf3;
    EBF4(e0, bf0, lm0, fz0) EBF4(e1, bf1, lm1, fz1)
    EBF4(e2, bf2, lm2, fz2) EBF4(e3, bf3, lm3, fz3)
    SUBSTEP(false)
    SUBSTEP(true)
    SUBSTEP(true)
    float wj;
    W_EVAL(wj);
    slw = fmaf(P.dbeta[j], wj, slw);
  }
  if (sub == 0) slw_out[gtraj] = slw;
}

// ---- logsumexp over n per batch column b
__global__ void k_reduce(const float* __restrict__ slw, float* __restrict__ out) {
  __shared__ float red[256];
  int b = blockIdx.x, t = threadIdx.x;
  float v0 = slw[t*128 + b];
  float v1 = slw[(t+256)*128 + b];
  float v2 = slw[(t+512)*128 + b];
  float v3 = slw[(t+768)*128 + b];
  float m = fmaxf(fmaxf(v0, v1), fmaxf(v2, v3));
  red[t] = m; __syncthreads();
  for (int s = 128; s > 0; s >>= 1) {
    if (t < s) red[t] = fmaxf(red[t], red[t+s]);
    __syncthreads();
  }
  m = red[0]; __syncthreads();
  float sum = expf(v0 - m) + expf(v1 - m) + expf(v2 - m) + expf(v3 - m);
  red[t] = sum; __syncthreads();
  for (int s = 128; s > 0; s >>= 1) {
    if (t < s) red[t] += red[t+s];
    __syncthreads();
  }
  if (t == 0) out[b] = m + logf(red[0]) - 6.93147180559945309f;  // - log(1024)
}

extern "C" void kernel_launch(void* const* d_in, const int* in_sizes, int n_in,
                              void* d_out, int out_size, void* d_ws, size_t ws_size,
                              hipStream_t stream) {
  const float* x    = (const float*)d_in[0];
  const float* Wenc = (const float*)d_in[1];
  const float* Wdec = (const float*)d_in[2];
  const float* qn   = (const float*)d_in[3];
  // d_in[4] (p_noise) is dead: momentum fully resampled every anneal step.
  float* ws  = (float*)d_ws;
  float* out = (float*)d_out;
  if (ws_size < (size_t)WS_TOTAL * sizeof(float)) return;

  KParams P;
  double bb[18];
  for (int i = 0; i < 18; ++i) {
    double tt = (double)i / 17.0;
    bb[i] = 1.0 / (1.0 + exp(-(8.0 * tt - 4.0)));
  }
  for (int i = 0; i < 18; ++i) P.beta[i] = (float)((bb[i] - bb[0]) / (bb[17] - bb[0]));
  for (int j = 0; j <= 16; ++j) P.dbeta[j] = P.beta[j+1] - P.beta[j];
  for (int k = 1; k <= 16; ++k) {
    uint32_t a, c;
    threefry2x32(0u, 42u, 0u, (uint32_t)k, a, c);  // fold_in(key(42), k)
    P.fk0[k-1] = a; P.fk1[k-1] = c;
  }

  hipLaunchKernelGGL(k_setup1, dim3(81), dim3(256), 0, stream, x, Wenc, Wdec, ws);
  hipLaunchKernelGGL(k_eig, dim3(1), dim3(256), 0, stream, ws);
  hipLaunchKernelGGL(k_setup2, dim3(32), dim3(256), 0, stream, ws);
  hipLaunchKernelGGL(k_setup3, dim3(1), dim3(128), 0, stream, ws);
  hipLaunchKernelGGL(k_setupfz, dim3(32), dim3(256), 0, stream, ws);
  hipLaunchKernelGGL(k_main, dim3(2048), dim3(256), 0, stream, qn, ws, ws + WS_SLW, P);
  hipLaunchKernelGGL(k_reduce, dim3(128), dim3(256), 0, stream, ws + WS_SLW, out);
}

// Round 12
// 1234.784 us; speedup vs baseline: 4.1759x; 1.0180x over previous
//
#include <hip/hip_runtime.h>
#include <math.h>
#include <stdint.h>

// AIS estimator: N=1024 samples, B=128, DIM=DX=64, K=16 anneal steps, 3 leapfrog.
// Round 12: k_eig latency cut (r11: 520us on 1 CU, pure barrier/serialization).
//  - pair-per-8-threads mapping (j = tid>>3): pair j's rows are touched only
//    by its own 8 threads, which sit in ONE wave -> wave-lockstep DS ordering
//    makes inline param computation race-free without a barrier. 3 -> 2
//    barriers/round; cs/pu staging arrays gone; row/col loops unrolled.
//  - rotations, order, arithmetic identical to r11 -> V bit-identical.
//  - k_main identical to r11 (690us, VALUBusy 82%) minus a dead fmaxf.
//  - Eigen-decoupled dynamics (r10/r11, absmax <= 1 bf16 ulp): z = y V,
//    diagonal leapfrog, 1 matvec/step (pz = p V), bit-exact JAX partitionable
//    threefry. p_noise input dead.

#define WS_A     0
#define WS_MU    4096
#define WS_C     12288
#define WS_XSQ   20480
#define WS_AMU   20608
#define WS_F     28800
#define WS_WC    36992
#define WS_V     37120
#define WS_LAM   41216
#define WS_FZ    41280
#define WS_SLW   49472
#define WS_TOTAL (WS_SLW + 131072)

#define LOG2PI 1.8378770664093453f

struct KParams {
  float beta[18];
  float dbeta[17];
  uint32_t fk0[16];
  uint32_t fk1[16];
};

__host__ __device__ static inline void threefry2x32(uint32_t ks0, uint32_t ks1,
                                                    uint32_t x0, uint32_t x1,
                                                    uint32_t& o0, uint32_t& o1) {
  uint32_t ks2 = ks0 ^ ks1 ^ 0x1BD11BDAu;
  x0 += ks0; x1 += ks1;
#define TFR(r) { x0 += x1; x1 = (x1 << (r)) | (x1 >> (32 - (r))); x1 ^= x0; }
  TFR(13) TFR(15) TFR(26) TFR(6)
  x0 += ks1; x1 += ks2 + 1u;
  TFR(17) TFR(29) TFR(16) TFR(24)
  x0 += ks2; x1 += ks0 + 2u;
  TFR(13) TFR(15) TFR(26) TFR(6)
  x0 += ks0; x1 += ks1 + 3u;
  TFR(17) TFR(29) TFR(16) TFR(24)
  x0 += ks1; x1 += ks2 + 4u;
  TFR(13) TFR(15) TFR(26) TFR(6)
  x0 += ks2; x1 += ks0 + 5u;
#undef TFR
  o0 = x0; o1 = x1;
}

__device__ __forceinline__ float u_from_bits(uint32_t bits) {
  const float LO = __uint_as_float(0xBF7FFFFFu);  // nextafter(-1,0) in f32
  float f = __uint_as_float((bits >> 9) | 0x3F800000u) - 1.0f;
  return fmaf(f, 2.0f, LO);   // f>=0 -> result >= LO; XLA's max(LO,.) is dead
}

// XLA ErfInv32 (Giles); __logf variant validated r11 (absmax = 1 bf16 ulp)
__device__ __forceinline__ float erfinv_f(float x) {
  float w = -__logf(fmaf(-x, x, 1.0f));
  float p;
  if (w < 5.0f) {
    w -= 2.5f;
    p = 2.81022636e-08f;
    p = fmaf(p, w, 3.43273939e-07f);
    p = fmaf(p, w, -3.5233877e-06f);
    p = fmaf(p, w, -4.39150654e-06f);
    p = fmaf(p, w, 0.00021858087f);
    p = fmaf(p, w, -0.00125372503f);
    p = fmaf(p, w, -0.00417768164f);
    p = fmaf(p, w, 0.246640727f);
    p = fmaf(p, w, 1.50140941f);
  } else {
    w = sqrtf(w) - 3.0f;
    p = -0.000200214257f;
    p = fmaf(p, w, 0.000100950558f);
    p = fmaf(p, w, 0.00134934322f);
    p = fmaf(p, w, -0.00367342844f);
    p = fmaf(p, w, 0.00573950773f);
    p = fmaf(p, w, -0.0076224613f);
    p = fmaf(p, w, 0.00943887047f);
    p = fmaf(p, w, 1.00167406f);
    p = fmaf(p, w, 2.83297682f);
  }
  return p * x;
}

// ---- setup1: A = Wdec Wdec^T ; mu[b][d] ; c[b][d] ; xsq[b]
__global__ void k_setup1(const float* __restrict__ x, const float* __restrict__ Wenc,
                         const float* __restrict__ Wdec, float* __restrict__ ws) {
  int t = blockIdx.x * 256 + threadIdx.x;
  if (t < 4096) {
    int i = t >> 6, j = t & 63;
    float s = 0;
    for (int e = 0; e < 64; ++e) s = fmaf(Wdec[i*64+e], Wdec[j*64+e], s);
    ws[WS_A + t] = s;
  } else if (t < 12288) {
    int u = t - 4096; int b = u >> 6, d = u & 63;
    float s = 0;
    for (int e = 0; e < 64; ++e) s = fmaf(x[b*64+e], Wenc[e*64+d], s);
    ws[WS_MU + u] = s;
  } else if (t < 20480) {
    int u = t - 12288; int b = u >> 6, d = u & 63;
    float s = 0;
    for (int e = 0; e < 64; ++e) s = fmaf(x[b*64+e], Wdec[d*64+e], s);
    ws[WS_C + u] = s;
  } else if (t < 20608) {
    int b = t - 20480;
    float s = 0;
    for (int e = 0; e < 64; ++e) s = fmaf(x[b*64+e], x[b*64+e], s);
    ws[WS_XSQ + b] = s;
  }
}

// ---- k_eig v2: cyclic Jacobi, 5 sweeps x 63 rounds, pitch 65 (2-way banks).
// Pair j owned by threads 8j..8j+7 (one wave owns 8 pairs). Row phase: params
// computed inline (pair rows are wave-local; DS issue order within a wave
// guarantees param reads precede row writes) -> no param barrier. 2 barriers.
#define EP 65
__global__ void k_eig(float* __restrict__ ws) {
  __shared__ float Am[64 * EP];
  __shared__ float Vm[64 * EP];
  const int tid = threadIdx.x;
  for (int i = tid; i < 4096; i += 256) {
    int r = i >> 6, c = i & 63;
    Am[r*EP + c] = ws[WS_A + i];
    Vm[r*EP + c] = (r == c) ? 1.0f : 0.0f;
  }
  __syncthreads();
  const int j = tid >> 3;       // pair id 0..31
  const int l8 = tid & 7;       // 0..7 within pair
  for (int sweep = 0; sweep < 5; ++sweep) {
    for (int r = 0; r < 63; ++r) {
      int u, v;
      if (j == 0) { u = 0; v = 1 + ((62 + r) % 63); }
      else { u = 1 + ((j - 1 + r) % 63); v = 1 + ((62 - j + r) % 63); }
      // params: redundant per 8 threads; reads pair-local rows only
      float app = Am[u*(EP+1)], aqq = Am[v*(EP+1)], apq = Am[u*EP+v];
      float c = 1.0f, s = 0.0f;
      if (fabsf(apq) > 1e-30f) {
        float tau = (aqq - app) / (2.0f * apq);
        float t = copysignf(1.0f / (fabsf(tau) + sqrtf(fmaf(tau, tau, 1.0f))), tau);
        c = 1.0f / sqrtf(fmaf(t, t, 1.0f));
        s = t * c;
      }
      // rows: A <- J^T A  (pair-local rows, 8 cols/thread, unrolled)
#pragma unroll
      for (int it = 0; it < 8; ++it) {
        int k = l8 + 8*it;
        float au = Am[u*EP+k], av = Am[v*EP+k];
        Am[u*EP+k] = c*au - s*av;
        Am[v*EP+k] = fmaf(s, au, c*av);
      }
      __syncthreads();
      // cols: A <- A J ; V <- V J  (pair-local cols, 8 rows/thread)
#pragma unroll
      for (int it = 0; it < 8; ++it) {
        int k = l8 + 8*it;
        float au = Am[k*EP+u], av = Am[k*EP+v];
        Am[k*EP+u] = c*au - s*av;
        Am[k*EP+v] = fmaf(s, au, c*av);
        float vu = Vm[k*EP+u], vv = Vm[k*EP+v];
        Vm[k*EP+u] = c*vu - s*vv;
        Vm[k*EP+v] = fmaf(s, vu, c*vv);
      }
      __syncthreads();
    }
  }
  for (int i = tid; i < 4096; i += 256) ws[WS_V + i] = Vm[(i >> 6)*EP + (i & 63)];
  if (tid < 64) ws[WS_LAM + tid] = Am[tid*(EP+1)];
}

// ---- setup2: amu[b][d] = (mu A)[d] ; f[b][d] = c - mu - amu
__global__ void k_setup2(float* __restrict__ ws) {
  int t = blockIdx.x * 256 + threadIdx.x;
  if (t < 8192) {
    int b = t >> 6, d = t & 63;
    float s = 0;
    for (int m = 0; m < 64; ++m) s = fmaf(ws[WS_MU + b*64+m], ws[WS_A + m*64+d], s);
    ws[WS_AMU + t] = s;
    ws[WS_F + t] = ws[WS_C + t] - ws[WS_MU + t] - s;
  }
}

// ---- setup3: wconst[b]
__global__ void k_setup3(float* __restrict__ ws) {
  int b = threadIdx.x;
  if (b < 128) {
    float muc = 0, musq = 0, muamu = 0;
    for (int d = 0; d < 64; ++d) {
      float m = ws[WS_MU + b*64+d];
      muc   = fmaf(m, ws[WS_C + b*64+d], muc);
      musq  = fmaf(m, m, musq);
      muamu = fmaf(m, ws[WS_AMU + b*64+d], muamu);
    }
    ws[WS_WC + b] = -32.0f * LOG2PI - 0.5f * ws[WS_XSQ + b]
                    + muc - 0.5f * musq - 0.5f * muamu;
  }
}

// ---- setup4: fz[b][d] = sum_m f[b][m] V[m][d]
__global__ void k_setupfz(float* __restrict__ ws) {
  int t = blockIdx.x * 256 + threadIdx.x;
  if (t < 8192) {
    int b = t >> 6, d = t & 63;
    float s = 0;
    for (int m = 0; m < 64; ++m) s = fmaf(ws[WS_F + b*64+m], ws[WS_V + m*64+d], s);
    ws[WS_FZ + t] = s;
  }
}

// ---- hot-loop macros: scalar/float4 only, nothing address-taken -----------

#define MVROW(QS, RP, T0, T1, T2, T3)                                        \
  {                                                                          \
    float4 a0v = *(const float4*)((RP) + 0);                                 \
    float4 a1v = *(const float4*)((RP) + 4);                                 \
    float4 a2v = *(const float4*)((RP) + 8);                                 \
    float4 a3v = *(const float4*)((RP) + 12);                                \
    T0.x = fmaf(QS, a0v.x, T0.x); T0.y = fmaf(QS, a0v.y, T0.y);              \
    T0.z = fmaf(QS, a0v.z, T0.z); T0.w = fmaf(QS, a0v.w, T0.w);              \
    T1.x = fmaf(QS, a1v.x, T1.x); T1.y = fmaf(QS, a1v.y, T1.y);              \
    T1.z = fmaf(QS, a1v.z, T1.z); T1.w = fmaf(QS, a1v.w, T1.w);              \
    T2.x = fmaf(QS, a2v.x, T2.x); T2.y = fmaf(QS, a2v.y, T2.y);              \
    T2.z = fmaf(QS, a2v.z, T2.z); T2.w = fmaf(QS, a2v.w, T2.w);              \
    T3.x = fmaf(QS, a3v.x, T3.x); T3.y = fmaf(QS, a3v.y, T3.y);              \
    T3.z = fmaf(QS, a3v.z, T3.z); T3.w = fmaf(QS, a3v.w, T3.w);              \
  }

#define MATVEC_V(T0, T1, T2, T3)                                             \
  T0 = make_float4(0.f, 0.f, 0.f, 0.f); T1 = T0; T2 = T0; T3 = T0;           \
  _Pragma("unroll 4")                                                        \
  for (int m4 = 0; m4 < 16; ++m4) {                                          \
    float4 q4 = *(const float4*)(pme + 4 * m4);                              \
    const float* rp = Vs + m4 * 256 + d0;                                    \
    MVROW(q4.x, rp,       T0, T1, T2, T3)                                    \
    MVROW(q4.y, rp + 64,  T0, T1, T2, T3)                                    \
    MVROW(q4.z, rp + 128, T0, T1, T2, T3)                                    \
    MVROW(q4.w, rp + 192, T0, T1, T2, T3)                                    \
  }

#define EBF1(EC, BC, LC, FC) EC = fmaf(bk, LC, 1.0f); BC = bk * FC;
#define EBF4(EV, BV, LV, FV)                                                 \
  EBF1(EV.x, BV.x, LV.x, FV.x) EBF1(EV.y, BV.y, LV.y, FV.y)                  \
  EBF1(EV.z, BV.z, LV.z, FV.z) EBF1(EV.w, BV.w, LV.w, FV.w)

#define LF1(ZC, PC, EC, BC, DBL)                                             \
  { float g = fmaf(-(EC), ZC, BC);                                           \
    PC = fmaf(0.025f, g, PC);                                                \
    if (DBL) PC = fmaf(0.025f, g, PC);                                       \
    ZC = fmaf(0.05f, PC, ZC); }
#define LF4(ZV, PV, EV, BV, DBL)                                             \
  LF1(ZV.x, PV.x, EV.x, BV.x, DBL) LF1(ZV.y, PV.y, EV.y, BV.y, DBL)          \
  LF1(ZV.z, PV.z, EV.z, BV.z, DBL) LF1(ZV.w, PV.w, EV.w, BV.w, DBL)
#define SUBSTEP(DBL)                                                         \
  LF4(z0, pz0, e0, bf0, DBL) LF4(z1, pz1, e1, bf1, DBL)                      \
  LF4(z2, pz2, e2, bf2, DBL) LF4(z3, pz3, e3, bf3, DBL)

#define WDOT4(S1, S2, FV, ZV, LV)                                            \
  { float t0 = LV.x * ZV.x; S2 = fmaf(t0, ZV.x, S2); S1 = fmaf(FV.x, ZV.x, S1); \
    float t1 = LV.y * ZV.y; S2 = fmaf(t1, ZV.y, S2); S1 = fmaf(FV.y, ZV.y, S1); \
    float t2 = LV.z * ZV.z; S2 = fmaf(t2, ZV.z, S2); S1 = fmaf(FV.z, ZV.z, S1); \
    float t3 = LV.w * ZV.w; S2 = fmaf(t3, ZV.w, S2); S1 = fmaf(FV.w, ZV.w, S1); }

#define W_EVAL(WOUT)                                                         \
  {                                                                          \
    float s1 = 0.f, s2 = 0.f;                                                \
    WDOT4(s1, s2, fz0, z0, lm0) WDOT4(s1, s2, fz1, z1, lm1)                  \
    WDOT4(s1, s2, fz2, z2, lm2) WDOT4(s1, s2, fz3, z3, lm3)                  \
    float v = fmaf(-0.5f, s2, s1);                                           \
    v += __shfl_xor(v, 1);                                                   \
    v += __shfl_xor(v, 2);                                                   \
    WOUT = v + wc;                                                           \
  }

#define DRAW(PC, IDX)                                                        \
  { uint32_t o0, o1;                                                         \
    threefry2x32(k0, k1, 0u, base + (IDX), o0, o1);                          \
    PC = 1.41421356f * erfinv_f(u_from_bits(o0 ^ o1)); }

#define STORE_P(A0, A1, A2, A3)                                              \
  *(float4*)(pme + d0 +  0) = A0; *(float4*)(pme + d0 +  4) = A1;            \
  *(float4*)(pme + d0 +  8) = A2; *(float4*)(pme + d0 + 12) = A3;

// ---- main: 4 lanes per trajectory (16 dims each), 64 trajectories/block
__global__ __launch_bounds__(256, 3) void k_main(const float* __restrict__ qn,
                                                 const float* __restrict__ ws,
                                                 float* __restrict__ slw_out,
                                                 KParams P) {
  __shared__ float Vs[4096];
  __shared__ float pls[64 * 68];  // [traj][dim], pad 68: float4 rows, 2-way bank
  const int tid = threadIdx.x;
  for (int i = tid; i < 4096; i += 256) Vs[i] = ws[WS_V + i];
  __syncthreads();

  const int ltraj = tid >> 2, sub = tid & 3;
  const int gtraj = blockIdx.x * 64 + ltraj;
  const int b = gtraj & 127;
  const int d0 = sub * 16;
  float* pme = pls + ltraj * 68;
  const float wc = ws[WS_WC + b];

  float4 fz0, fz1, fz2, fz3, lm0, lm1, lm2, lm3;
  {
    const float4* fzP = (const float4*)(ws + WS_FZ + b*64 + d0);
    fz0 = fzP[0]; fz1 = fzP[1]; fz2 = fzP[2]; fz3 = fzP[3];
    const float4* lmP = (const float4*)(ws + WS_LAM + d0);
    lm0 = lmP[0]; lm1 = lmP[1]; lm2 = lmP[2]; lm3 = lmP[3];
  }

  float4 z0, z1, z2, z3, pz0, pz1, pz2, pz3;
  float slw = 0.0f;

  // j = 0: y0 = q_noise (y-domain) -> z0 = qn . V
  {
    const float4* qn4 = (const float4*)(qn + (size_t)gtraj*64 + d0);
    float4 a0 = qn4[0], a1 = qn4[1], a2 = qn4[2], a3 = qn4[3];
    STORE_P(a0, a1, a2, a3)
  }
  MATVEC_V(z0, z1, z2, z3)
  {
    float w0;
    W_EVAL(w0);
    slw = fmaf(P.dbeta[0], w0, slw);
  }

  const uint32_t base = (uint32_t)gtraj * 64u + (uint32_t)d0;
  for (int j = 1; j <= 16; ++j) {
    const float bk = P.beta[j];
    const uint32_t k0 = P.fk0[j-1], k1 = P.fk1[j-1];
    // momentum refresh (original basis, bit-exact), staged to LDS for rotation
    {
      float4 a0, a1, a2, a3;
      DRAW(a0.x,  0u) DRAW(a0.y,  1u) DRAW(a0.z,  2u) DRAW(a0.w,  3u)
      DRAW(a1.x,  4u) DRAW(a1.y,  5u) DRAW(a1.z,  6u) DRAW(a1.w,  7u)
      DRAW(a2.x,  8u) DRAW(a2.y,  9u) DRAW(a2.z, 10u) DRAW(a2.w, 11u)
      DRAW(a3.x, 12u) DRAW(a3.y, 13u) DRAW(a3.z, 14u) DRAW(a3.w, 15u)
      STORE_P(a0, a1, a2, a3)
    }
    MATVEC_V(pz0, pz1, pz2, pz3)          // pz = p . V
    float4 e0, e1, e2, e3, bf0, bf1, bf2, bf3;
    EBF4(e0, bf0, lm0, fz0) EBF4(e1, bf1, lm1, fz1)
    EBF4(e2, bf2, lm2, fz2) EBF4(e3, bf3, lm3, fz3)
    SUBSTEP(false)
    SUBSTEP(true)
    SUBSTEP(true)
    float wj;
    W_EVAL(wj);
    slw = fmaf(P.dbeta[j], wj, slw);
  }
  if (sub == 0) slw_out[gtraj] = slw;
}

// ---- logsumexp over n per batch column b
__global__ void k_reduce(const float* __restrict__ slw, float* __restrict__ out) {
  __shared__ float red[256];
  int b = blockIdx.x, t = threadIdx.x;
  float v0 = slw[t*128 + b];
  float v1 = slw[(t+256)*128 + b];
  float v2 = slw[(t+512)*128 + b];
  float v3 = slw[(t+768)*128 + b];
  float m = fmaxf(fmaxf(v0, v1), fmaxf(v2, v3));
  red[t] = m; __syncthreads();
  for (int s = 128; s > 0; s >>= 1) {
    if (t < s) red[t] = fmaxf(red[t], red[t+s]);
    __syncthreads();
  }
  m = red[0]; __syncthreads();
  float sum = expf(v0 - m) + expf(v1 - m) + expf(v2 - m) + expf(v3 - m);
  red[t] = sum; __syncthreads();
  for (int s = 128; s > 0; s >>= 1) {
    if (t < s) red[t] += red[t+s];
    __syncthreads();
  }
  if (t == 0) out[b] = m + logf(red[0]) - 6.93147180559945309f;  // - log(1024)
}

extern "C" void kernel_launch(void* const* d_in, const int* in_sizes, int n_in,
                              void* d_out, int out_size, void* d_ws, size_t ws_size,
                              hipStream_t stream) {
  const float* x    = (const float*)d_in[0];
  const float* Wenc = (const float*)d_in[1];
  const float* Wdec = (const float*)d_in[2];
  const float* qn   = (const float*)d_in[3];
  // d_in[4] (p_noise) is dead: momentum fully resampled every anneal step.
  float* ws  = (float*)d_ws;
  float* out = (float*)d_out;
  if (ws_size < (size_t)WS_TOTAL * sizeof(float)) return;

  KParams P;
  double bb[18];
  for (int i = 0; i < 18; ++i) {
    double tt = (double)i / 17.0;
    bb[i] = 1.0 / (1.0 + exp(-(8.0 * tt - 4.0)));
  }
  for (int i = 0; i < 18; ++i) P.beta[i] = (float)((bb[i] - bb[0]) / (bb[17] - bb[0]));
  for (int j = 0; j <= 16; ++j) P.dbeta[j] = P.beta[j+1] - P.beta[j];
  for (int k = 1; k <= 16; ++k) {
    uint32_t a, c;
    threefry2x32(0u, 42u, 0u, (uint32_t)k, a, c);  // fold_in(key(42), k)
    P.fk0[k-1] = a; P.fk1[k-1] = c;
  }

  hipLaunchKernelGGL(k_setup1, dim3(81), dim3(256), 0, stream, x, Wenc, Wdec, ws);
  hipLaunchKernelGGL(k_eig, dim3(1), dim3(256), 0, stream, ws);
  hipLaunchKernelGGL(k_setup2, dim3(32), dim3(256), 0, stream, ws);
  hipLaunchKernelGGL(k_setup3, dim3(1), dim3(128), 0, stream, ws);
  hipLaunchKernelGGL(k_setupfz, dim3(32), dim3(256), 0, stream, ws);
  hipLaunchKernelGGL(k_main, dim3(2048), dim3(256), 0, stream, qn, ws, ws + WS_SLW, P);
  hipLaunchKernelGGL(k_reduce, dim3(128), dim3(256), 0, stream, ws + WS_SLW, out);
}

// Round 13
// 1166.738 us; speedup vs baseline: 4.4194x; 1.0583x over previous
//
#include <hip/hip_runtime.h>
#include <math.h>
#include <stdint.h>

// AIS estimator: N=1024 samples, B=128, DIM=DX=64, K=16 anneal steps, 3 leapfrog.
// Round 13: k_eig two-sided fused update. r12 evidence: removing a barrier
// didn't move k_eig (~490us) -> cost is the serial chain of 3 dependent LDS
// phases (params/row/col), each paying issue+latency+waitcnt-drain at 1
// wave/SIMD. Fix: the 32 disjoint rotations partition A into 32x32 blocks of
// 2x2; compute B' = Ri^T B Rj per block in ONE pass (each element read once,
// written once). Same two rounding steps, same order as r12 -> V, Lam
// BIT-IDENTICAL (absmax must stay exactly 1.0 = discriminator for races).
//  - k_main identical to r12 (686us, VALUBusy 82%).
//  - Eigen-decoupled dynamics (r10-r12): z = y V, diagonal leapfrog, 1
//    matvec/step (pz = p V), bit-exact JAX partitionable threefry.
//    p_noise input dead.

#define WS_A     0
#define WS_MU    4096
#define WS_C     12288
#define WS_XSQ   20480
#define WS_AMU   20608
#define WS_F     28800
#define WS_WC    36992
#define WS_V     37120
#define WS_LAM   41216
#define WS_FZ    41280
#define WS_SLW   49472
#define WS_TOTAL (WS_SLW + 131072)

#define LOG2PI 1.8378770664093453f

struct KParams {
  float beta[18];
  float dbeta[17];
  uint32_t fk0[16];
  uint32_t fk1[16];
};

__host__ __device__ static inline void threefry2x32(uint32_t ks0, uint32_t ks1,
                                                    uint32_t x0, uint32_t x1,
                                                    uint32_t& o0, uint32_t& o1) {
  uint32_t ks2 = ks0 ^ ks1 ^ 0x1BD11BDAu;
  x0 += ks0; x1 += ks1;
#define TFR(r) { x0 += x1; x1 = (x1 << (r)) | (x1 >> (32 - (r))); x1 ^= x0; }
  TFR(13) TFR(15) TFR(26) TFR(6)
  x0 += ks1; x1 += ks2 + 1u;
  TFR(17) TFR(29) TFR(16) TFR(24)
  x0 += ks2; x1 += ks0 + 2u;
  TFR(13) TFR(15) TFR(26) TFR(6)
  x0 += ks0; x1 += ks1 + 3u;
  TFR(17) TFR(29) TFR(16) TFR(24)
  x0 += ks1; x1 += ks2 + 4u;
  TFR(13) TFR(15) TFR(26) TFR(6)
  x0 += ks2; x1 += ks0 + 5u;
#undef TFR
  o0 = x0; o1 = x1;
}

__device__ __forceinline__ float u_from_bits(uint32_t bits) {
  const float LO = __uint_as_float(0xBF7FFFFFu);  // nextafter(-1,0) in f32
  float f = __uint_as_float((bits >> 9) | 0x3F800000u) - 1.0f;
  return fmaf(f, 2.0f, LO);   // f>=0 -> result >= LO; XLA's max(LO,.) is dead
}

// XLA ErfInv32 (Giles); __logf variant validated r11/r12 (absmax = 1 bf16 ulp)
__device__ __forceinline__ float erfinv_f(float x) {
  float w = -__logf(fmaf(-x, x, 1.0f));
  float p;
  if (w < 5.0f) {
    w -= 2.5f;
    p = 2.81022636e-08f;
    p = fmaf(p, w, 3.43273939e-07f);
    p = fmaf(p, w, -3.5233877e-06f);
    p = fmaf(p, w, -4.39150654e-06f);
    p = fmaf(p, w, 0.00021858087f);
    p = fmaf(p, w, -0.00125372503f);
    p = fmaf(p, w, -0.00417768164f);
    p = fmaf(p, w, 0.246640727f);
    p = fmaf(p, w, 1.50140941f);
  } else {
    w = sqrtf(w) - 3.0f;
    p = -0.000200214257f;
    p = fmaf(p, w, 0.000100950558f);
    p = fmaf(p, w, 0.00134934322f);
    p = fmaf(p, w, -0.00367342844f);
    p = fmaf(p, w, 0.00573950773f);
    p = fmaf(p, w, -0.0076224613f);
    p = fmaf(p, w, 0.00943887047f);
    p = fmaf(p, w, 1.00167406f);
    p = fmaf(p, w, 2.83297682f);
  }
  return p * x;
}

// ---- setup1: A = Wdec Wdec^T ; mu[b][d] ; c[b][d] ; xsq[b]
__global__ void k_setup1(const float* __restrict__ x, const float* __restrict__ Wenc,
                         const float* __restrict__ Wdec, float* __restrict__ ws) {
  int t = blockIdx.x * 256 + threadIdx.x;
  if (t < 4096) {
    int i = t >> 6, j = t & 63;
    float s = 0;
    for (int e = 0; e < 64; ++e) s = fmaf(Wdec[i*64+e], Wdec[j*64+e], s);
    ws[WS_A + t] = s;
  } else if (t < 12288) {
    int u = t - 4096; int b = u >> 6, d = u & 63;
    float s = 0;
    for (int e = 0; e < 64; ++e) s = fmaf(x[b*64+e], Wenc[e*64+d], s);
    ws[WS_MU + u] = s;
  } else if (t < 20480) {
    int u = t - 12288; int b = u >> 6, d = u & 63;
    float s = 0;
    for (int e = 0; e < 64; ++e) s = fmaf(x[b*64+e], Wdec[d*64+e], s);
    ws[WS_C + u] = s;
  } else if (t < 20608) {
    int b = t - 20480;
    float s = 0;
    for (int e = 0; e < 64; ++e) s = fmaf(x[b*64+e], x[b*64+e], s);
    ws[WS_XSQ + b] = s;
  }
}

// ---- k_eig v3: cyclic Jacobi, 5 sweeps x 63 rounds, pitch 65 (2-way banks).
// FUSED two-sided update: rotations are disjoint -> A partitions into 32x32
// independent 2x2 blocks; B' = Ri^T B Rj computed in registers, one read +
// one write per element per round. Rounding steps identical to r12's
// row-then-col -> bit-identical V/Lam. 2 barriers/round.
#define EP 65
__global__ void k_eig(float* __restrict__ ws) {
  __shared__ float Am[64 * EP];
  __shared__ float Vm[64 * EP];
  __shared__ float cs_c[32], cs_s[32];
  __shared__ int ppu[32], ppv[32];
  const int tid = threadIdx.x;
  for (int i = tid; i < 4096; i += 256) {
    int r = i >> 6, c = i & 63;
    Am[r*EP + c] = ws[WS_A + i];
    Vm[r*EP + c] = (r == c) ? 1.0f : 0.0f;
  }
  __syncthreads();
  for (int sweep = 0; sweep < 5; ++sweep) {
    for (int r = 0; r < 63; ++r) {
      // params: one thread per pair (tournament schedule identical to r11/r12)
      if (tid < 32) {
        int j = tid;
        int u, v;
        if (j == 0) { u = 0; v = 1 + ((62 + r) % 63); }
        else { u = 1 + ((j - 1 + r) % 63); v = 1 + ((62 - j + r) % 63); }
        float app = Am[u*(EP+1)], aqq = Am[v*(EP+1)], apq = Am[u*EP+v];
        float c = 1.0f, s = 0.0f;
        if (fabsf(apq) > 1e-30f) {
          float tau = (aqq - app) / (2.0f * apq);
          float t = copysignf(1.0f / (fabsf(tau) + sqrtf(fmaf(tau, tau, 1.0f))), tau);
          c = 1.0f / sqrtf(fmaf(t, t, 1.0f));
          s = t * c;
        }
        ppu[j] = u; ppv[j] = v; cs_c[j] = c; cs_s[j] = s;
      }
      __syncthreads();
      // A: fused two-sided, 1024 2x2 blocks, 4 per thread.
#pragma unroll
      for (int it = 0; it < 4; ++it) {
        int idx = tid + 256*it;
        int i = idx >> 5, j = idx & 31;
        int ui = ppu[i], vi = ppv[i], uj = ppu[j], vj = ppv[j];
        float ci = cs_c[i], si = cs_s[i], cj = cs_c[j], sj = cs_s[j];
        float a = Am[ui*EP+uj], bb = Am[ui*EP+vj];
        float d = Am[vi*EP+uj], e  = Am[vi*EP+vj];
        // left rotation Ri^T (r12 row-phase expressions, f32-rounded)
        float r0u = ci*a  - si*d;
        float r1u = fmaf(si, a,  ci*d);
        float r0v = ci*bb - si*e;
        float r1v = fmaf(si, bb, ci*e);
        // right rotation Rj (r12 col-phase expressions)
        Am[ui*EP+uj] = cj*r0u - sj*r0v;
        Am[ui*EP+vj] = fmaf(sj, r0u, cj*r0v);
        Am[vi*EP+uj] = cj*r1u - sj*r1v;
        Am[vi*EP+vj] = fmaf(sj, r1u, cj*r1v);
      }
      // V <- V J: 32 pairs x 64 rows, 8 per thread
#pragma unroll
      for (int it = 0; it < 8; ++it) {
        int idx = tid + 256*it;
        int j = idx >> 6, k = idx & 63;
        int u = ppu[j], v = ppv[j];
        float c = cs_c[j], s = cs_s[j];
        float vu = Vm[k*EP+u], vv = Vm[k*EP+v];
        Vm[k*EP+u] = c*vu - s*vv;
        Vm[k*EP+v] = fmaf(s, vu, c*vv);
      }
      __syncthreads();
    }
  }
  for (int i = tid; i < 4096; i += 256) ws[WS_V + i] = Vm[(i >> 6)*EP + (i & 63)];
  if (tid < 64) ws[WS_LAM + tid] = Am[tid*(EP+1)];
}

// ---- setup2: amu[b][d] = (mu A)[d] ; f[b][d] = c - mu - amu
__global__ void k_setup2(float* __restrict__ ws) {
  int t = blockIdx.x * 256 + threadIdx.x;
  if (t < 8192) {
    int b = t >> 6, d = t & 63;
    float s = 0;
    for (int m = 0; m < 64; ++m) s = fmaf(ws[WS_MU + b*64+m], ws[WS_A + m*64+d], s);
    ws[WS_AMU + t] = s;
    ws[WS_F + t] = ws[WS_C + t] - ws[WS_MU + t] - s;
  }
}

// ---- setup3: wconst[b]
__global__ void k_setup3(float* __restrict__ ws) {
  int b = threadIdx.x;
  if (b < 128) {
    float muc = 0, musq = 0, muamu = 0;
    for (int d = 0; d < 64; ++d) {
      float m = ws[WS_MU + b*64+d];
      muc   = fmaf(m, ws[WS_C + b*64+d], muc);
      musq  = fmaf(m, m, musq);
      muamu = fmaf(m, ws[WS_AMU + b*64+d], muamu);
    }
    ws[WS_WC + b] = -32.0f * LOG2PI - 0.5f * ws[WS_XSQ + b]
                    + muc - 0.5f * musq - 0.5f * muamu;
  }
}

// ---- setup4: fz[b][d] = sum_m f[b][m] V[m][d]
__global__ void k_setupfz(float* __restrict__ ws) {
  int t = blockIdx.x * 256 + threadIdx.x;
  if (t < 8192) {
    int b = t >> 6, d = t & 63;
    float s = 0;
    for (int m = 0; m < 64; ++m) s = fmaf(ws[WS_F + b*64+m], ws[WS_V + m*64+d], s);
    ws[WS_FZ + t] = s;
  }
}

// ---- hot-loop macros: scalar/float4 only, nothing address-taken -----------

#define MVROW(QS, RP, T0, T1, T2, T3)                                        \
  {                                                                          \
    float4 a0v = *(const float4*)((RP) + 0);                                 \
    float4 a1v = *(const float4*)((RP) + 4);                                 \
    float4 a2v = *(const float4*)((RP) + 8);                                 \
    float4 a3v = *(const float4*)((RP) + 12);                                \
    T0.x = fmaf(QS, a0v.x, T0.x); T0.y = fmaf(QS, a0v.y, T0.y);              \
    T0.z = fmaf(QS, a0v.z, T0.z); T0.w = fmaf(QS, a0v.w, T0.w);              \
    T1.x = fmaf(QS, a1v.x, T1.x); T1.y = fmaf(QS, a1v.y, T1.y);              \
    T1.z = fmaf(QS, a1v.z, T1.z); T1.w = fmaf(QS, a1v.w, T1.w);              \
    T2.x = fmaf(QS, a2v.x, T2.x); T2.y = fmaf(QS, a2v.y, T2.y);              \
    T2.z = fmaf(QS, a2v.z, T2.z); T2.w = fmaf(QS, a2v.w, T2.w);              \
    T3.x = fmaf(QS, a3v.x, T3.x); T3.y = fmaf(QS, a3v.y, T3.y);              \
    T3.z = fmaf(QS, a3v.z, T3.z); T3.w = fmaf(QS, a3v.w, T3.w);              \
  }

#define MATVEC_V(T0, T1, T2, T3)                                             \
  T0 = make_float4(0.f, 0.f, 0.f, 0.f); T1 = T0; T2 = T0; T3 = T0;           \
  _Pragma("unroll 4")                                                        \
  for (int m4 = 0; m4 < 16; ++m4) {                                          \
    float4 q4 = *(const float4*)(pme + 4 * m4);                              \
    const float* rp = Vs + m4 * 256 + d0;                                    \
    MVROW(q4.x, rp,       T0, T1, T2, T3)                                    \
    MVROW(q4.y, rp + 64,  T0, T1, T2, T3)                                    \
    MVROW(q4.z, rp + 128, T0, T1, T2, T3)                                    \
    MVROW(q4.w, rp + 192, T0, T1, T2, T3)                                    \
  }

#define EBF1(EC, BC, LC, FC) EC = fmaf(bk, LC, 1.0f); BC = bk * FC;
#define EBF4(EV, BV, LV, FV)                                                 \
  EBF1(EV.x, BV.x, LV.x, FV.x) EBF1(EV.y, BV.y, LV.y, FV.y)                  \
  EBF1(EV.z, BV.z, LV.z, FV.z) EBF1(EV.w, BV.w, LV.w, FV.w)

#define LF1(ZC, PC, EC, BC, DBL)                                             \
  { float g = fmaf(-(EC), ZC, BC);                                           \
    PC = fmaf(0.025f, g, PC);                                                \
    if (DBL) PC = fmaf(0.025f, g, PC);                                       \
    ZC = fmaf(0.05f, PC, ZC); }
#define LF4(ZV, PV, EV, BV, DBL)                                             \
  LF1(ZV.x, PV.x, EV.x, BV.x, DBL) LF1(ZV.y, PV.y, EV.y, BV.y, DBL)          \
  LF1(ZV.z, PV.z, EV.z, BV.z, DBL) LF1(ZV.w, PV.w, EV.w, BV.w, DBL)
#define SUBSTEP(DBL)                                                         \
  LF4(z0, pz0, e0, bf0, DBL) LF4(z1, pz1, e1, bf1, DBL)                      \
  LF4(z2, pz2, e2, bf2, DBL) LF4(z3, pz3, e3, bf3, DBL)

#define WDOT4(S1, S2, FV, ZV, LV)                                            \
  { float t0 = LV.x * ZV.x; S2 = fmaf(t0, ZV.x, S2); S1 = fmaf(FV.x, ZV.x, S1); \
    float t1 = LV.y * ZV.y; S2 = fmaf(t1, ZV.y, S2); S1 = fmaf(FV.y, ZV.y, S1); \
    float t2 = LV.z * ZV.z; S2 = fmaf(t2, ZV.z, S2); S1 = fmaf(FV.z, ZV.z, S1); \
    float t3 = LV.w * ZV.w; S2 = fmaf(t3, ZV.w, S2); S1 = fmaf(FV.w, ZV.w, S1); }

#define W_EVAL(WOUT)                                                         \
  {                                                                          \
    float s1 = 0.f, s2 = 0.f;                                                \
    WDOT4(s1, s2, fz0, z0, lm0) WDOT4(s1, s2, fz1, z1, lm1)                  \
    WDOT4(s1, s2, fz2, z2, lm2) WDOT4(s1, s2, fz3, z3, lm3)                  \
    float v = fmaf(-0.5f, s2, s1);                                           \
    v += __shfl_xor(v, 1);                                                   \
    v += __shfl_xor(v, 2);                                                   \
    WOUT = v + wc;                                                           \
  }

#define DRAW(PC, IDX)                                                        \
  { uint32_t o0, o1;                                                         \
    threefry2x32(k0, k1, 0u, base + (IDX), o0, o1);                          \
    PC = 1.41421356f * erfinv_f(u_from_bits(o0 ^ o1)); }

#define STORE_P(A0, A1, A2, A3)                                              \
  *(float4*)(pme + d0 +  0) = A0; *(float4*)(pme + d0 +  4) = A1;            \
  *(float4*)(pme + d0 +  8) = A2; *(float4*)(pme + d0 + 12) = A3;

// ---- main: 4 lanes per trajectory (16 dims each), 64 trajectories/block
__global__ __launch_bounds__(256, 3) void k_main(const float* __restrict__ qn,
                                                 const float* __restrict__ ws,
                                                 float* __restrict__ slw_out,
                                                 KParams P) {
  __shared__ float Vs[4096];
  __shared__ float pls[64 * 68];  // [traj][dim], pad 68: float4 rows, 2-way bank
  const int tid = threadIdx.x;
  for (int i = tid; i < 4096; i += 256) Vs[i] = ws[WS_V + i];
  __syncthreads();

  const int ltraj = tid >> 2, sub = tid & 3;
  const int gtraj = blockIdx.x * 64 + ltraj;
  const int b = gtraj & 127;
  const int d0 = sub * 16;
  float* pme = pls + ltraj * 68;
  const float wc = ws[WS_WC + b];

  float4 fz0, fz1, fz2, fz3, lm0, lm1, lm2, lm3;
  {
    const float4* fzP = (const float4*)(ws + WS_FZ + b*64 + d0);
    fz0 = fzP[0]; fz1 = fzP[1]; fz2 = fzP[2]; fz3 = fzP[3];
    const float4* lmP = (const float4*)(ws + WS_LAM + d0);
    lm0 = lmP[0]; lm1 = lmP[1]; lm2 = lmP[2]; lm3 = lmP[3];
  }

  float4 z0, z1, z2, z3, pz0, pz1, pz2, pz3;
  float slw = 0.0f;

  // j = 0: y0 = q_noise (y-domain) -> z0 = qn . V
  {
    const float4* qn4 = (const float4*)(qn + (size_t)gtraj*64 + d0);
    float4 a0 = qn4[0], a1 = qn4[1], a2 = qn4[2], a3 = qn4[3];
    STORE_P(a0, a1, a2, a3)
  }
  MATVEC_V(z0, z1, z2, z3)
  {
    float w0;
    W_EVAL(w0);
    slw = fmaf(P.dbeta[0], w0, slw);
  }

  const uint32_t base = (uint32_t)gtraj * 64u + (uint32_t)d0;
  for (int j = 1; j <= 16; ++j) {
    const float bk = P.beta[j];
    const uint32_t k0 = P.fk0[j-1], k1 = P.fk1[j-1];
    // momentum refresh (original basis, bit-exact), staged to LDS for rotation
    {
      float4 a0, a1, a2, a3;
      DRAW(a0.x,  0u) DRAW(a0.y,  1u) DRAW(a0.z,  2u) DRAW(a0.w,  3u)
      DRAW(a1.x,  4u) DRAW(a1.y,  5u) DRAW(a1.z,  6u) DRAW(a1.w,  7u)
      DRAW(a2.x,  8u) DRAW(a2.y,  9u) DRAW(a2.z, 10u) DRAW(a2.w, 11u)
      DRAW(a3.x, 12u) DRAW(a3.y, 13u) DRAW(a3.z, 14u) DRAW(a3.w, 15u)
      STORE_P(a0, a1, a2, a3)
    }
    MATVEC_V(pz0, pz1, pz2, pz3)          // pz = p . V
    float4 e0, e1, e2, e3, bf0, bf1, bf2, bf3;
    EBF4(e0, bf0, lm0, fz0) EBF4(e1, bf1, lm1, fz1)
    EBF4(e2, bf2, lm2, fz2) EBF4(e3, bf3, lm3, fz3)
    SUBSTEP(false)
    SUBSTEP(true)
    SUBSTEP(true)
    float wj;
    W_EVAL(wj);
    slw = fmaf(P.dbeta[j], wj, slw);
  }
  if (sub == 0) slw_out[gtraj] = slw;
}

// ---- logsumexp over n per batch column b
__global__ void k_reduce(const float* __restrict__ slw, float* __restrict__ out) {
  __shared__ float red[256];
  int b = blockIdx.x, t = threadIdx.x;
  float v0 = slw[t*128 + b];
  float v1 = slw[(t+256)*128 + b];
  float v2 = slw[(t+512)*128 + b];
  float v3 = slw[(t+768)*128 + b];
  float m = fmaxf(fmaxf(v0, v1), fmaxf(v2, v3));
  red[t] = m; __syncthreads();
  for (int s = 128; s > 0; s >>= 1) {
    if (t < s) red[t] = fmaxf(red[t], red[t+s]);
    __syncthreads();
  }
  m = red[0]; __syncthreads();
  float sum = expf(v0 - m) + expf(v1 - m) + expf(v2 - m) + expf(v3 - m);
  red[t] = sum; __syncthreads();
  for (int s = 128; s > 0; s >>= 1) {
    if (t < s) red[t] += red[t+s];
    __syncthreads();
  }
  if (t == 0) out[b] = m + logf(red[0]) - 6.93147180559945309f;  // - log(1024)
}

extern "C" void kernel_launch(void* const* d_in, const int* in_sizes, int n_in,
                              void* d_out, int out_size, void* d_ws, size_t ws_size,
                              hipStream_t stream) {
  const float* x    = (const float*)d_in[0];
  const float* Wenc = (const float*)d_in[1];
  const float* Wdec = (const float*)d_in[2];
  const float* qn   = (const float*)d_in[3];
  // d_in[4] (p_noise) is dead: momentum fully resampled every anneal step.
  float* ws  = (float*)d_ws;
  float* out = (float*)d_out;
  if (ws_size < (size_t)WS_TOTAL * sizeof(float)) return;

  KParams P;
  double bb[18];
  for (int i = 0; i < 18; ++i) {
    double tt = (double)i / 17.0;
    bb[i] = 1.0 / (1.0 + exp(-(8.0 * tt - 4.0)));
  }
  for (int i = 0; i < 18; ++i) P.beta[i] = (float)((bb[i] - bb[0]) / (bb[17] - bb[0]));
  for (int j = 0; j <= 16; ++j) P.dbeta[j] = P.beta[j+1] - P.beta[j];
  for (int k = 1; k <= 16; ++k) {
    uint32_t a, c;
    threefry2x32(0u, 42u, 0u, (uint32_t)k, a, c);  // fold_in(key(42), k)
    P.fk0[k-1] = a; P.fk1[k-1] = c;
  }

  hipLaunchKernelGGL(k_setup1, dim3(81), dim3(256), 0, stream, x, Wenc, Wdec, ws);
  hipLaunchKernelGGL(k_eig, dim3(1), dim3(256), 0, stream, ws);
  hipLaunchKernelGGL(k_setup2, dim3(32), dim3(256), 0, stream, ws);
  hipLaunchKernelGGL(k_setup3, dim3(1), dim3(128), 0, stream, ws);
  hipLaunchKernelGGL(k_setupfz, dim3(32), dim3(256), 0, stream, ws);
  hipLaunchKernelGGL(k_main, dim3(2048), dim3(256), 0, stream, qn, ws, ws + WS_SLW, P);
  hipLaunchKernelGGL(k_reduce, dim3(128), dim3(256), 0, stream, ws + WS_SLW, out);
}

// Round 14
// 992.152 us; speedup vs baseline: 5.1971x; 1.1760x over previous
//
#include <hip/hip_runtime.h>
#include <math.h>
#include <stdint.h>

// AIS estimator: N=1024 samples, B=128, DIM=DX=64, K=16 anneal steps, 3 leapfrog.
// Round 14: MFMA-ized k_main. Per wave the per-step rotation pz = p.V is a
// 16(traj) x 64 x 64 GEMM fragment -> v_mfma_f32_16x16x32_f16, f16 hi/lo
// 3-term split (PhiVhi + PhiVlo + PloVhi, err ~2^-21). RNG is counter-based:
// each lane draws exactly the normals its A-fragment needs (A[m=lane&15]
// [k=quad*8+j], HW-verified) -> still bit-exact JAX threefry. State lives in
// MFMA C-layout (traj=quad*4+reg, dim=nt*16+lane&15); diagonal leapfrog is
// elementwise (layout-free); w-reduce via 16-lane shfl_xor groups.
// Replaces 1024 VALU FMA + 272 ds_read_b128 per step with 24 MFMA + 16
// ds_read_b128. LDS 33.8 -> 16.4 KB. k_eig = r13 (bit-identical, absmax 1.0).
// B-frag layout assumed symmetric to A (B[k=quad*8+j][n=lane&15]) — if
// transposed, absmax blows up ~O(100) and next round swaps k/n in k_setupVF.

#define WS_A     0
#define WS_MU    4096
#define WS_C     12288
#define WS_XSQ   20480
#define WS_AMU   20608
#define WS_F     28800
#define WS_WC    36992
#define WS_V     37120
#define WS_LAM   41216
#define WS_FZ    41280
#define WS_VF    49472
#define WS_SLW   53568
#define WS_TOTAL (WS_SLW + 131072)

#define LOG2PI 1.8378770664093453f

typedef _Float16 half8_t __attribute__((ext_vector_type(8)));
typedef float f4_t __attribute__((ext_vector_type(4)));
typedef unsigned int uint4_t __attribute__((ext_vector_type(4)));

struct KParams {
  float beta[18];
  float dbeta[17];
  uint32_t fk0[16];
  uint32_t fk1[16];
};

__host__ __device__ static inline void threefry2x32(uint32_t ks0, uint32_t ks1,
                                                    uint32_t x0, uint32_t x1,
                                                    uint32_t& o0, uint32_t& o1) {
  uint32_t ks2 = ks0 ^ ks1 ^ 0x1BD11BDAu;
  x0 += ks0; x1 += ks1;
#define TFR(r) { x0 += x1; x1 = (x1 << (r)) | (x1 >> (32 - (r))); x1 ^= x0; }
  TFR(13) TFR(15) TFR(26) TFR(6)
  x0 += ks1; x1 += ks2 + 1u;
  TFR(17) TFR(29) TFR(16) TFR(24)
  x0 += ks2; x1 += ks0 + 2u;
  TFR(13) TFR(15) TFR(26) TFR(6)
  x0 += ks0; x1 += ks1 + 3u;
  TFR(17) TFR(29) TFR(16) TFR(24)
  x0 += ks1; x1 += ks2 + 4u;
  TFR(13) TFR(15) TFR(26) TFR(6)
  x0 += ks2; x1 += ks0 + 5u;
#undef TFR
  o0 = x0; o1 = x1;
}

__device__ __forceinline__ float u_from_bits(uint32_t bits) {
  const float LO = __uint_as_float(0xBF7FFFFFu);  // nextafter(-1,0) in f32
  float f = __uint_as_float((bits >> 9) | 0x3F800000u) - 1.0f;
  return fmaf(f, 2.0f, LO);
}

// XLA ErfInv32 (Giles); __logf variant validated r11-r13 (absmax = 1 bf16 ulp)
__device__ __forceinline__ float erfinv_f(float x) {
  float w = -__logf(fmaf(-x, x, 1.0f));
  float p;
  if (w < 5.0f) {
    w -= 2.5f;
    p = 2.81022636e-08f;
    p = fmaf(p, w, 3.43273939e-07f);
    p = fmaf(p, w, -3.5233877e-06f);
    p = fmaf(p, w, -4.39150654e-06f);
    p = fmaf(p, w, 0.00021858087f);
    p = fmaf(p, w, -0.00125372503f);
    p = fmaf(p, w, -0.00417768164f);
    p = fmaf(p, w, 0.246640727f);
    p = fmaf(p, w, 1.50140941f);
  } else {
    w = sqrtf(w) - 3.0f;
    p = -0.000200214257f;
    p = fmaf(p, w, 0.000100950558f);
    p = fmaf(p, w, 0.00134934322f);
    p = fmaf(p, w, -0.00367342844f);
    p = fmaf(p, w, 0.00573950773f);
    p = fmaf(p, w, -0.0076224613f);
    p = fmaf(p, w, 0.00943887047f);
    p = fmaf(p, w, 1.00167406f);
    p = fmaf(p, w, 2.83297682f);
  }
  return p * x;
}

// ---- setup1: A = Wdec Wdec^T ; mu[b][d] ; c[b][d] ; xsq[b]
__global__ void k_setup1(const float* __restrict__ x, const float* __restrict__ Wenc,
                         const float* __restrict__ Wdec, float* __restrict__ ws) {
  int t = blockIdx.x * 256 + threadIdx.x;
  if (t < 4096) {
    int i = t >> 6, j = t & 63;
    float s = 0;
    for (int e = 0; e < 64; ++e) s = fmaf(Wdec[i*64+e], Wdec[j*64+e], s);
    ws[WS_A + t] = s;
  } else if (t < 12288) {
    int u = t - 4096; int b = u >> 6, d = u & 63;
    float s = 0;
    for (int e = 0; e < 64; ++e) s = fmaf(x[b*64+e], Wenc[e*64+d], s);
    ws[WS_MU + u] = s;
  } else if (t < 20480) {
    int u = t - 12288; int b = u >> 6, d = u & 63;
    float s = 0;
    for (int e = 0; e < 64; ++e) s = fmaf(x[b*64+e], Wdec[d*64+e], s);
    ws[WS_C + u] = s;
  } else if (t < 20608) {
    int b = t - 20480;
    float s = 0;
    for (int e = 0; e < 64; ++e) s = fmaf(x[b*64+e], x[b*64+e], s);
    ws[WS_XSQ + b] = s;
  }
}

// ---- k_eig (r13, validated bit-identical): cyclic Jacobi, 5 sweeps x 63
// rounds, pitch 65, fused two-sided 2x2-block update. 2 barriers/round.
#define EP 65
__global__ void k_eig(float* __restrict__ ws) {
  __shared__ float Am[64 * EP];
  __shared__ float Vm[64 * EP];
  __shared__ float cs_c[32], cs_s[32];
  __shared__ int ppu[32], ppv[32];
  const int tid = threadIdx.x;
  for (int i = tid; i < 4096; i += 256) {
    int r = i >> 6, c = i & 63;
    Am[r*EP + c] = ws[WS_A + i];
    Vm[r*EP + c] = (r == c) ? 1.0f : 0.0f;
  }
  __syncthreads();
  for (int sweep = 0; sweep < 5; ++sweep) {
    for (int r = 0; r < 63; ++r) {
      if (tid < 32) {
        int j = tid;
        int u, v;
        if (j == 0) { u = 0; v = 1 + ((62 + r) % 63); }
        else { u = 1 + ((j - 1 + r) % 63); v = 1 + ((62 - j + r) % 63); }
        float app = Am[u*(EP+1)], aqq = Am[v*(EP+1)], apq = Am[u*EP+v];
        float c = 1.0f, s = 0.0f;
        if (fabsf(apq) > 1e-30f) {
          float tau = (aqq - app) / (2.0f * apq);
          float t = copysignf(1.0f / (fabsf(tau) + sqrtf(fmaf(tau, tau, 1.0f))), tau);
          c = 1.0f / sqrtf(fmaf(t, t, 1.0f));
          s = t * c;
        }
        ppu[j] = u; ppv[j] = v; cs_c[j] = c; cs_s[j] = s;
      }
      __syncthreads();
#pragma unroll
      for (int it = 0; it < 4; ++it) {
        int idx = tid + 256*it;
        int i = idx >> 5, j = idx & 31;
        int ui = ppu[i], vi = ppv[i], uj = ppu[j], vj = ppv[j];
        float ci = cs_c[i], si = cs_s[i], cj = cs_c[j], sj = cs_s[j];
        float a = Am[ui*EP+uj], bb = Am[ui*EP+vj];
        float d = Am[vi*EP+uj], e  = Am[vi*EP+vj];
        float r0u = ci*a  - si*d;
        float r1u = fmaf(si, a,  ci*d);
        float r0v = ci*bb - si*e;
        float r1v = fmaf(si, bb, ci*e);
        Am[ui*EP+uj] = cj*r0u - sj*r0v;
        Am[ui*EP+vj] = fmaf(sj, r0u, cj*r0v);
        Am[vi*EP+uj] = cj*r1u - sj*r1v;
        Am[vi*EP+vj] = fmaf(sj, r1u, cj*r1v);
      }
#pragma unroll
      for (int it = 0; it < 8; ++it) {
        int idx = tid + 256*it;
        int j = idx >> 6, k = idx & 63;
        int u = ppu[j], v = ppv[j];
        float c = cs_c[j], s = cs_s[j];
        float vu = Vm[k*EP+u], vv = Vm[k*EP+v];
        Vm[k*EP+u] = c*vu - s*vv;
        Vm[k*EP+v] = fmaf(s, vu, c*vv);
      }
      __syncthreads();
    }
  }
  for (int i = tid; i < 4096; i += 256) ws[WS_V + i] = Vm[(i >> 6)*EP + (i & 63)];
  if (tid < 64) ws[WS_LAM + tid] = Am[tid*(EP+1)];
}

// ---- setup2: amu[b][d] = (mu A)[d] ; f[b][d] = c - mu - amu
__global__ void k_setup2(float* __restrict__ ws) {
  int t = blockIdx.x * 256 + threadIdx.x;
  if (t < 8192) {
    int b = t >> 6, d = t & 63;
    float s = 0;
    for (int m = 0; m < 64; ++m) s = fmaf(ws[WS_MU + b*64+m], ws[WS_A + m*64+d], s);
    ws[WS_AMU + t] = s;
    ws[WS_F + t] = ws[WS_C + t] - ws[WS_MU + t] - s;
  }
}

// ---- setup3: wconst[b]
__global__ void k_setup3(float* __restrict__ ws) {
  int b = threadIdx.x;
  if (b < 128) {
    float muc = 0, musq = 0, muamu = 0;
    for (int d = 0; d < 64; ++d) {
      float m = ws[WS_MU + b*64+d];
      muc   = fmaf(m, ws[WS_C + b*64+d], muc);
      musq  = fmaf(m, m, musq);
      muamu = fmaf(m, ws[WS_AMU + b*64+d], muamu);
    }
    ws[WS_WC + b] = -32.0f * LOG2PI - 0.5f * ws[WS_XSQ + b]
                    + muc - 0.5f * musq - 0.5f * muamu;
  }
}

// ---- setup4: fz[b][d] = sum_m f[b][m] V[m][d]
__global__ void k_setupfz(float* __restrict__ ws) {
  int t = blockIdx.x * 256 + threadIdx.x;
  if (t < 8192) {
    int b = t >> 6, d = t & 63;
    float s = 0;
    for (int m = 0; m < 64; ++m) s = fmaf(ws[WS_F + b*64+m], ws[WS_V + m*64+d], s);
    ws[WS_FZ + t] = s;
  }
}

// ---- setupVF: pack V into f16 hi/lo MFMA B-fragments.
// Frag F = (t*2+kt)*4+nt, lane L: element j holds B[k=kt*32+(L>>4)*8+j]
// [n=nt*16+(L&15)] = V[k][n]; t=0 hi (f16 RTNE), t=1 lo (residual).
__global__ void k_setupVF(float* __restrict__ ws) {
  int idx = blockIdx.x * 256 + threadIdx.x;   // 0..1023
  if (idx >= 1024) return;
  int lane = idx & 63, F = idx >> 6;
  int t = F >> 3, kt = (F >> 2) & 1, nt = F & 3;
  int n = nt*16 + (lane & 15);
  int k0 = kt*32 + ((lane >> 4) & 3)*8;
  uint32_t out[4];
  for (int jj = 0; jj < 4; ++jj) {
    float v0 = ws[WS_V + (k0 + 2*jj    )*64 + n];
    float v1 = ws[WS_V + (k0 + 2*jj + 1)*64 + n];
    _Float16 h0, h1;
    if (t == 0) { h0 = (_Float16)v0; h1 = (_Float16)v1; }
    else {
      _Float16 a0 = (_Float16)v0, a1 = (_Float16)v1;
      h0 = (_Float16)(v0 - (float)a0);
      h1 = (_Float16)(v1 - (float)a1);
    }
    unsigned short u0 = __builtin_bit_cast(unsigned short, h0);
    unsigned short u1 = __builtin_bit_cast(unsigned short, h1);
    out[jj] = (uint32_t)u0 | ((uint32_t)u1 << 16);
  }
  uint32_t* dst = (uint32_t*)ws + WS_VF + idx*4;
  dst[0] = out[0]; dst[1] = out[1]; dst[2] = out[2]; dst[3] = out[3];
}

// ---- k_main hot-loop macros ------------------------------------------------

#define DRAW(PC, IDX)                                                        \
  { uint32_t o0, o1;                                                         \
    threefry2x32(k0, k1, 0u, base + (IDX), o0, o1);                          \
    PC = 1.41421356f * erfinv_f(u_from_bits(o0 ^ o1)); }

#define SPLIT1(AH, AL, J, VV)                                                \
  { _Float16 hh = (_Float16)(VV); AH[J] = hh;                                \
    AL[J] = (_Float16)((VV) - (float)hh); }

#define DRAWSPLIT8(AH, AL, KB)                                               \
  { float dd;                                                                \
    DRAW(dd, (KB)+0) SPLIT1(AH, AL, 0, dd)                                   \
    DRAW(dd, (KB)+1) SPLIT1(AH, AL, 1, dd)                                   \
    DRAW(dd, (KB)+2) SPLIT1(AH, AL, 2, dd)                                   \
    DRAW(dd, (KB)+3) SPLIT1(AH, AL, 3, dd)                                   \
    DRAW(dd, (KB)+4) SPLIT1(AH, AL, 4, dd)                                   \
    DRAW(dd, (KB)+5) SPLIT1(AH, AL, 5, dd)                                   \
    DRAW(dd, (KB)+6) SPLIT1(AH, AL, 6, dd)                                   \
    DRAW(dd, (KB)+7) SPLIT1(AH, AL, 7, dd) }

#define FRAGB(T, KT, NT)                                                     \
  __builtin_bit_cast(half8_t, VF[(((T)*2+(KT))*4+(NT))*64 + lane])

#define ROT1(ZO, NT, AH0, AL0, AH1, AL1)                                     \
  { half8_t bh0 = FRAGB(0,0,NT), bh1 = FRAGB(0,1,NT);                        \
    half8_t bl0 = FRAGB(1,0,NT), bl1 = FRAGB(1,1,NT);                        \
    f4_t aa = {0.f, 0.f, 0.f, 0.f};                                          \
    aa = __builtin_amdgcn_mfma_f32_16x16x32_f16(AH0, bh0, aa, 0, 0, 0);      \
    aa = __builtin_amdgcn_mfma_f32_16x16x32_f16(AH1, bh1, aa, 0, 0, 0);      \
    aa = __builtin_amdgcn_mfma_f32_16x16x32_f16(AL0, bh0, aa, 0, 0, 0);      \
    aa = __builtin_amdgcn_mfma_f32_16x16x32_f16(AL1, bh1, aa, 0, 0, 0);      \
    aa = __builtin_amdgcn_mfma_f32_16x16x32_f16(AH0, bl0, aa, 0, 0, 0);      \
    aa = __builtin_amdgcn_mfma_f32_16x16x32_f16(AH1, bl1, aa, 0, 0, 0);      \
    ZO = aa; }

#define ROTATE4(O0, O1, O2, O3, AH0, AL0, AH1, AL1)                          \
  ROT1(O0, 0, AH0, AL0, AH1, AL1) ROT1(O1, 1, AH0, AL0, AH1, AL1)            \
  ROT1(O2, 2, AH0, AL0, AH1, AL1) ROT1(O3, 3, AH0, AL0, AH1, AL1)

// diagonal leapfrog: g = bk*(fz - lm z) - z ; p += h/2 g (x2 at boundary);
// z += h p
#define LF1N(ZC, PC, LM, FC, DBL)                                            \
  { float gg = fmaf(bk, fmaf(-(LM), ZC, FC), -(ZC));                         \
    PC = fmaf(0.025f, gg, PC);                                               \
    if (DBL) PC = fmaf(0.025f, gg, PC);                                      \
    ZC = fmaf(0.05f, PC, ZC); }
#define LF4N(ZV, PV, LM, FV, DBL)                                            \
  LF1N(ZV.x, PV.x, LM, FV.x, DBL) LF1N(ZV.y, PV.y, LM, FV.y, DBL)            \
  LF1N(ZV.z, PV.z, LM, FV.z, DBL) LF1N(ZV.w, PV.w, LM, FV.w, DBL)
#define SUBSTEPN(DBL)                                                        \
  LF4N(z0, pz0, lmS0, fzv0, DBL) LF4N(z1, pz1, lmS1, fzv1, DBL)              \
  LF4N(z2, pz2, lmS2, fzv2, DBL) LF4N(z3, pz3, lmS3, fzv3, DBL)

// w partial: components r=0..3 (trajs g4*4+r); reduce over 16-lane group
#define W_EVALN(WOUT)                                                        \
  { f4_t s1 = fzv0*z0 + fzv1*z1 + fzv2*z2 + fzv3*z3;                         \
    f4_t s2 = (lmS0*z0)*z0 + (lmS1*z1)*z1 + (lmS2*z2)*z2 + (lmS3*z3)*z3;     \
    f4_t vv = s1 - 0.5f*s2;                                                  \
    float r0 = vv.x, r1 = vv.y, r2 = vv.z, r3 = vv.w;                        \
    r0 += __shfl_xor(r0, 1); r1 += __shfl_xor(r1, 1);                        \
    r2 += __shfl_xor(r2, 1); r3 += __shfl_xor(r3, 1);                        \
    r0 += __shfl_xor(r0, 2); r1 += __shfl_xor(r1, 2);                        \
    r2 += __shfl_xor(r2, 2); r3 += __shfl_xor(r3, 2);                        \
    r0 += __shfl_xor(r0, 4); r1 += __shfl_xor(r1, 4);                        \
    r2 += __shfl_xor(r2, 4); r3 += __shfl_xor(r3, 4);                        \
    r0 += __shfl_xor(r0, 8); r1 += __shfl_xor(r1, 8);                        \
    r2 += __shfl_xor(r2, 8); r3 += __shfl_xor(r3, 8);                        \
    float wsel = (cw == 0) ? r0 : ((cw == 1) ? r1 : ((cw == 2) ? r2 : r3));  \
    WOUT = wsel + wcs; }

// ---- main: MFMA rotation; wave = 16 trajs; 4 waves/block, 2048 blocks
__global__ __launch_bounds__(256, 2) void k_main(const float* __restrict__ qn,
                                                 const float* __restrict__ ws,
                                                 float* __restrict__ slw_out,
                                                 KParams P) {
  __shared__ uint4_t VF[1024];   // 16 KB: V f16 hi/lo B-fragments
  const int tid = threadIdx.x;
  {
    const uint4_t* src = (const uint4_t*)((const uint32_t*)ws + WS_VF);
    for (int i = tid; i < 1024; i += 256) VF[i] = src[i];
  }
  __syncthreads();

  const int lane = tid & 63;
  const int wv = tid >> 6;
  const int cw = lane & 15;              // MFMA col; also A-operand row m
  const int g4 = lane >> 4;              // quad id
  const int koff = g4 * 8;               // A-fragment k offset
  const int trajBase = blockIdx.x * 64 + wv * 16;
  const uint32_t base = (uint32_t)(trajBase + cw) * 64u;   // RNG row base

  // C-layout constants: component r <-> traj g4*4+r; dim = nt*16 + cw
  const int b0 = (trajBase + g4*4 + 0) & 127;
  const int b1 = (trajBase + g4*4 + 1) & 127;
  const int b2 = (trajBase + g4*4 + 2) & 127;
  const int b3 = (trajBase + g4*4 + 3) & 127;
  f4_t fzv0, fzv1, fzv2, fzv3;
  fzv0.x = ws[WS_FZ + b0*64 + cw];      fzv0.y = ws[WS_FZ + b1*64 + cw];
  fzv0.z = ws[WS_FZ + b2*64 + cw];      fzv0.w = ws[WS_FZ + b3*64 + cw];
  fzv1.x = ws[WS_FZ + b0*64 + 16 + cw]; fzv1.y = ws[WS_FZ + b1*64 + 16 + cw];
  fzv1.z = ws[WS_FZ + b2*64 + 16 + cw]; fzv1.w = ws[WS_FZ + b3*64 + 16 + cw];
  fzv2.x = ws[WS_FZ + b0*64 + 32 + cw]; fzv2.y = ws[WS_FZ + b1*64 + 32 + cw];
  fzv2.z = ws[WS_FZ + b2*64 + 32 + cw]; fzv2.w = ws[WS_FZ + b3*64 + 32 + cw];
  fzv3.x = ws[WS_FZ + b0*64 + 48 + cw]; fzv3.y = ws[WS_FZ + b1*64 + 48 + cw];
  fzv3.z = ws[WS_FZ + b2*64 + 48 + cw]; fzv3.w = ws[WS_FZ + b3*64 + 48 + cw];
  const float lmS0 = ws[WS_LAM + cw];
  const float lmS1 = ws[WS_LAM + 16 + cw];
  const float lmS2 = ws[WS_LAM + 32 + cw];
  const float lmS3 = ws[WS_LAM + 48 + cw];
  const float wcs = ws[WS_WC + ((trajBase + g4*4 + (cw & 3)) & 127)];

  f4_t z0, z1, z2, z3, pz0, pz1, pz2, pz3;
  float slw = 0.0f;

  // j = 0: z0 = qn . V  (qn read at A-fragment positions; f16 3-term split)
  {
    const float* qp = qn + (size_t)base;
    f4_t qa = *(const f4_t*)(qp + koff);
    f4_t qb = *(const f4_t*)(qp + koff + 4);
    f4_t qc = *(const f4_t*)(qp + 32 + koff);
    f4_t qd = *(const f4_t*)(qp + 32 + koff + 4);
    half8_t ah0, al0, ah1, al1;
    SPLIT1(ah0, al0, 0, qa.x) SPLIT1(ah0, al0, 1, qa.y)
    SPLIT1(ah0, al0, 2, qa.z) SPLIT1(ah0, al0, 3, qa.w)
    SPLIT1(ah0, al0, 4, qb.x) SPLIT1(ah0, al0, 5, qb.y)
    SPLIT1(ah0, al0, 6, qb.z) SPLIT1(ah0, al0, 7, qb.w)
    SPLIT1(ah1, al1, 0, qc.x) SPLIT1(ah1, al1, 1, qc.y)
    SPLIT1(ah1, al1, 2, qc.z) SPLIT1(ah1, al1, 3, qc.w)
    SPLIT1(ah1, al1, 4, qd.x) SPLIT1(ah1, al1, 5, qd.y)
    SPLIT1(ah1, al1, 6, qd.z) SPLIT1(ah1, al1, 7, qd.w)
    ROTATE4(z0, z1, z2, z3, ah0, al0, ah1, al1)
  }
  {
    float w0;
    W_EVALN(w0);
    slw = fmaf(P.dbeta[0], w0, slw);
  }

  for (int j = 1; j <= 16; ++j) {
    const float bk = P.beta[j];
    const uint32_t k0 = P.fk0[j-1], k1 = P.fk1[j-1];
    // momentum refresh: draws at this lane's A-fragment indices (bit-exact)
    half8_t ah0, al0, ah1, al1;
    DRAWSPLIT8(ah0, al0, koff)
    DRAWSPLIT8(ah1, al1, 32 + koff)
    ROTATE4(pz0, pz1, pz2, pz3, ah0, al0, ah1, al1)   // pz = p . V
    SUBSTEPN(false)
    SUBSTEPN(true)
    SUBSTEPN(true)
    float wj;
    W_EVALN(wj);
    slw = fmaf(P.dbeta[j], wj, slw);
  }
  if (cw < 4) slw_out[trajBase + g4*4 + cw] = slw;
}

// ---- logsumexp over n per batch column b
__global__ void k_reduce(const float* __restrict__ slw, float* __restrict__ out) {
  __shared__ float red[256];
  int b = blockIdx.x, t = threadIdx.x;
  float v0 = slw[t*128 + b];
  float v1 = slw[(t+256)*128 + b];
  float v2 = slw[(t+512)*128 + b];
  float v3 = slw[(t+768)*128 + b];
  float m = fmaxf(fmaxf(v0, v1), fmaxf(v2, v3));
  red[t] = m; __syncthreads();
  for (int s = 128; s > 0; s >>= 1) {
    if (t < s) red[t] = fmaxf(red[t], red[t+s]);
    __syncthreads();
  }
  m = red[0]; __syncthreads();
  float sum = expf(v0 - m) + expf(v1 - m) + expf(v2 - m) + expf(v3 - m);
  red[t] = sum; __syncthreads();
  for (int s = 128; s > 0; s >>= 1) {
    if (t < s) red[t] += red[t+s];
    __syncthreads();
  }
  if (t == 0) out[b] = m + logf(red[0]) - 6.93147180559945309f;  // - log(1024)
}

extern "C" void kernel_launch(void* const* d_in, const int* in_sizes, int n_in,
                              void* d_out, int out_size, void* d_ws, size_t ws_size,
                              hipStream_t stream) {
  const float* x    = (const float*)d_in[0];
  const float* Wenc = (const float*)d_in[1];
  const float* Wdec = (const float*)d_in[2];
  const float* qn   = (const float*)d_in[3];
  // d_in[4] (p_noise) is dead: momentum fully resampled every anneal step.
  float* ws  = (float*)d_ws;
  float* out = (float*)d_out;
  if (ws_size < (size_t)WS_TOTAL * sizeof(float)) return;

  KParams P;
  double bb[18];
  for (int i = 0; i < 18; ++i) {
    double tt = (double)i / 17.0;
    bb[i] = 1.0 / (1.0 + exp(-(8.0 * tt - 4.0)));
  }
  for (int i = 0; i < 18; ++i) P.beta[i] = (float)((bb[i] - bb[0]) / (bb[17] - bb[0]));
  for (int j = 0; j <= 16; ++j) P.dbeta[j] = P.beta[j+1] - P.beta[j];
  for (int k = 1; k <= 16; ++k) {
    uint32_t a, c;
    threefry2x32(0u, 42u, 0u, (uint32_t)k, a, c);  // fold_in(key(42), k)
    P.fk0[k-1] = a; P.fk1[k-1] = c;
  }

  hipLaunchKernelGGL(k_setup1, dim3(81), dim3(256), 0, stream, x, Wenc, Wdec, ws);
  hipLaunchKernelGGL(k_eig, dim3(1), dim3(256), 0, stream, ws);
  hipLaunchKernelGGL(k_setup2, dim3(32), dim3(256), 0, stream, ws);
  hipLaunchKernelGGL(k_setup3, dim3(1), dim3(128), 0, stream, ws);
  hipLaunchKernelGGL(k_setupfz, dim3(32), dim3(256), 0, stream, ws);
  hipLaunchKernelGGL(k_setupVF, dim3(4), dim3(256), 0, stream, ws);
  hipLaunchKernelGGL(k_main, dim3(2048), dim3(256), 0, stream, qn, ws, ws + WS_SLW, P);
  hipLaunchKernelGGL(k_reduce, dim3(128), dim3(256), 0, stream, ws + WS_SLW, out);
}

// Round 15
// 766.382 us; speedup vs baseline: 6.7282x; 1.2946x over previous
//
#include <hip/hip_runtime.h>
#include <math.h>
#include <stdint.h>

// AIS estimator: N=1024 samples, B=128, DIM=DX=64, K=16 anneal steps, 3 leapfrog.
// Round 15: k_eig width scaling. r14: k_eig = 486us = 49% of total, 315 serial
// rounds on 1 CU, VALUBusy 0.07% -> pure latency chain (params -> A-update ->
// V-update, each 4-8 LDS-latencies deep with only 4 waves resident).
//  - k_eig: 256 -> 1024 threads (16 waves): A-update 1 block/thread, V-update
//    2/thread -> each phase 1-2 LDS round-trips; 16 waves hide latency.
//  - sweeps 5 -> 4 (quadratic convergence: off-diag ~1e-8 rel by sweep 4;
//    absmax sits at the bf16-ulp floor 1.0 for 5 and 8 sweeps alike).
//  - setupfz + setupVF merged into one launch.
//  - k_main unchanged from r14 (~450us): MFMA f16 3-term split rotation
//    (pz = p.V), bit-exact JAX partitionable threefry at A-fragment indices,
//    diagonal leapfrog in eigenbasis, C-layout state. absmax 1.0 verified.

#define WS_A     0
#define WS_MU    4096
#define WS_C     12288
#define WS_XSQ   20480
#define WS_AMU   20608
#define WS_F     28800
#define WS_WC    36992
#define WS_V     37120
#define WS_LAM   41216
#define WS_FZ    41280
#define WS_VF    49472
#define WS_SLW   53568
#define WS_TOTAL (WS_SLW + 131072)

#define LOG2PI 1.8378770664093453f

typedef _Float16 half8_t __attribute__((ext_vector_type(8)));
typedef float f4_t __attribute__((ext_vector_type(4)));
typedef unsigned int uint4_t __attribute__((ext_vector_type(4)));

struct KParams {
  float beta[18];
  float dbeta[17];
  uint32_t fk0[16];
  uint32_t fk1[16];
};

__host__ __device__ static inline void threefry2x32(uint32_t ks0, uint32_t ks1,
                                                    uint32_t x0, uint32_t x1,
                                                    uint32_t& o0, uint32_t& o1) {
  uint32_t ks2 = ks0 ^ ks1 ^ 0x1BD11BDAu;
  x0 += ks0; x1 += ks1;
#define TFR(r) { x0 += x1; x1 = (x1 << (r)) | (x1 >> (32 - (r))); x1 ^= x0; }
  TFR(13) TFR(15) TFR(26) TFR(6)
  x0 += ks1; x1 += ks2 + 1u;
  TFR(17) TFR(29) TFR(16) TFR(24)
  x0 += ks2; x1 += ks0 + 2u;
  TFR(13) TFR(15) TFR(26) TFR(6)
  x0 += ks0; x1 += ks1 + 3u;
  TFR(17) TFR(29) TFR(16) TFR(24)
  x0 += ks1; x1 += ks2 + 4u;
  TFR(13) TFR(15) TFR(26) TFR(6)
  x0 += ks2; x1 += ks0 + 5u;
#undef TFR
  o0 = x0; o1 = x1;
}

__device__ __forceinline__ float u_from_bits(uint32_t bits) {
  const float LO = __uint_as_float(0xBF7FFFFFu);  // nextafter(-1,0) in f32
  float f = __uint_as_float((bits >> 9) | 0x3F800000u) - 1.0f;
  return fmaf(f, 2.0f, LO);
}

// XLA ErfInv32 (Giles); __logf variant validated r11-r14 (absmax = 1 bf16 ulp)
__device__ __forceinline__ float erfinv_f(float x) {
  float w = -__logf(fmaf(-x, x, 1.0f));
  float p;
  if (w < 5.0f) {
    w -= 2.5f;
    p = 2.81022636e-08f;
    p = fmaf(p, w, 3.43273939e-07f);
    p = fmaf(p, w, -3.5233877e-06f);
    p = fmaf(p, w, -4.39150654e-06f);
    p = fmaf(p, w, 0.00021858087f);
    p = fmaf(p, w, -0.00125372503f);
    p = fmaf(p, w, -0.00417768164f);
    p = fmaf(p, w, 0.246640727f);
    p = fmaf(p, w, 1.50140941f);
  } else {
    w = sqrtf(w) - 3.0f;
    p = -0.000200214257f;
    p = fmaf(p, w, 0.000100950558f);
    p = fmaf(p, w, 0.00134934322f);
    p = fmaf(p, w, -0.00367342844f);
    p = fmaf(p, w, 0.00573950773f);
    p = fmaf(p, w, -0.0076224613f);
    p = fmaf(p, w, 0.00943887047f);
    p = fmaf(p, w, 1.00167406f);
    p = fmaf(p, w, 2.83297682f);
  }
  return p * x;
}

// ---- setup1: A = Wdec Wdec^T ; mu[b][d] ; c[b][d] ; xsq[b]
__global__ void k_setup1(const float* __restrict__ x, const float* __restrict__ Wenc,
                         const float* __restrict__ Wdec, float* __restrict__ ws) {
  int t = blockIdx.x * 256 + threadIdx.x;
  if (t < 4096) {
    int i = t >> 6, j = t & 63;
    float s = 0;
    for (int e = 0; e < 64; ++e) s = fmaf(Wdec[i*64+e], Wdec[j*64+e], s);
    ws[WS_A + t] = s;
  } else if (t < 12288) {
    int u = t - 4096; int b = u >> 6, d = u & 63;
    float s = 0;
    for (int e = 0; e < 64; ++e) s = fmaf(x[b*64+e], Wenc[e*64+d], s);
    ws[WS_MU + u] = s;
  } else if (t < 20480) {
    int u = t - 12288; int b = u >> 6, d = u & 63;
    float s = 0;
    for (int e = 0; e < 64; ++e) s = fmaf(x[b*64+e], Wdec[d*64+e], s);
    ws[WS_C + u] = s;
  } else if (t < 20608) {
    int b = t - 20480;
    float s = 0;
    for (int e = 0; e < 64; ++e) s = fmaf(x[b*64+e], x[b*64+e], s);
    ws[WS_XSQ + b] = s;
  }
}

// ---- k_eig v4: cyclic Jacobi, 4 sweeps x 63 rounds, pitch 65, fused
// two-sided 2x2-block update (r13/r14 arithmetic, unchanged rounding order).
// 1024 threads: A-update 1 block/thread, V-update 2/thread, 16 waves hide
// LDS latency. 2 barriers/round.
#define EP 65
__global__ __launch_bounds__(1024) void k_eig(float* __restrict__ ws) {
  __shared__ float Am[64 * EP];
  __shared__ float Vm[64 * EP];
  __shared__ float cs_c[32], cs_s[32];
  __shared__ int ppu[32], ppv[32];
  const int tid = threadIdx.x;
  for (int i = tid; i < 4096; i += 1024) {
    int r = i >> 6, c = i & 63;
    Am[r*EP + c] = ws[WS_A + i];
    Vm[r*EP + c] = (r == c) ? 1.0f : 0.0f;
  }
  __syncthreads();
  for (int sweep = 0; sweep < 4; ++sweep) {
    for (int r = 0; r < 63; ++r) {
      if (tid < 32) {
        int j = tid;
        int u, v;
        if (j == 0) { u = 0; v = 1 + ((62 + r) % 63); }
        else { u = 1 + ((j - 1 + r) % 63); v = 1 + ((62 - j + r) % 63); }
        float app = Am[u*(EP+1)], aqq = Am[v*(EP+1)], apq = Am[u*EP+v];
        float c = 1.0f, s = 0.0f;
        if (fabsf(apq) > 1e-30f) {
          float tau = (aqq - app) / (2.0f * apq);
          float t = copysignf(1.0f / (fabsf(tau) + sqrtf(fmaf(tau, tau, 1.0f))), tau);
          c = 1.0f / sqrtf(fmaf(t, t, 1.0f));
          s = t * c;
        }
        ppu[j] = u; ppv[j] = v; cs_c[j] = c; cs_s[j] = s;
      }
      __syncthreads();
      // A: fused two-sided, 1024 2x2 blocks, 1 per thread
      {
        int i = tid >> 5, j = tid & 31;
        int ui = ppu[i], vi = ppv[i], uj = ppu[j], vj = ppv[j];
        float ci = cs_c[i], si = cs_s[i], cj = cs_c[j], sj = cs_s[j];
        float a = Am[ui*EP+uj], bb = Am[ui*EP+vj];
        float d = Am[vi*EP+uj], e  = Am[vi*EP+vj];
        float r0u = ci*a  - si*d;
        float r1u = fmaf(si, a,  ci*d);
        float r0v = ci*bb - si*e;
        float r1v = fmaf(si, bb, ci*e);
        Am[ui*EP+uj] = cj*r0u - sj*r0v;
        Am[ui*EP+vj] = fmaf(sj, r0u, cj*r0v);
        Am[vi*EP+uj] = cj*r1u - sj*r1v;
        Am[vi*EP+vj] = fmaf(sj, r1u, cj*r1v);
      }
      // V <- V J: 32 pairs x 64 rows, 2 per thread
#pragma unroll
      for (int it = 0; it < 2; ++it) {
        int idx = tid + 1024*it;
        int j = idx >> 6, k = idx & 63;
        int u = ppu[j], v = ppv[j];
        float c = cs_c[j], s = cs_s[j];
        float vu = Vm[k*EP+u], vv = Vm[k*EP+v];
        Vm[k*EP+u] = c*vu - s*vv;
        Vm[k*EP+v] = fmaf(s, vu, c*vv);
      }
      __syncthreads();
    }
  }
  for (int i = tid; i < 4096; i += 1024) ws[WS_V + i] = Vm[(i >> 6)*EP + (i & 63)];
  if (tid < 64) ws[WS_LAM + tid] = Am[tid*(EP+1)];
}

// ---- setup2: amu[b][d] = (mu A)[d] ; f[b][d] = c - mu - amu
__global__ void k_setup2(float* __restrict__ ws) {
  int t = blockIdx.x * 256 + threadIdx.x;
  if (t < 8192) {
    int b = t >> 6, d = t & 63;
    float s = 0;
    for (int m = 0; m < 64; ++m) s = fmaf(ws[WS_MU + b*64+m], ws[WS_A + m*64+d], s);
    ws[WS_AMU + t] = s;
    ws[WS_F + t] = ws[WS_C + t] - ws[WS_MU + t] - s;
  }
}

// ---- setup3: wconst[b]
__global__ void k_setup3(float* __restrict__ ws) {
  int b = threadIdx.x;
  if (b < 128) {
    float muc = 0, musq = 0, muamu = 0;
    for (int d = 0; d < 64; ++d) {
      float m = ws[WS_MU + b*64+d];
      muc   = fmaf(m, ws[WS_C + b*64+d], muc);
      musq  = fmaf(m, m, musq);
      muamu = fmaf(m, ws[WS_AMU + b*64+d], muamu);
    }
    ws[WS_WC + b] = -32.0f * LOG2PI - 0.5f * ws[WS_XSQ + b]
                    + muc - 0.5f * musq - 0.5f * muamu;
  }
}

// ---- setupfv (merged fz + VF): blocks 0-31: fz = f V; blocks 32-35: pack V
// into f16 hi/lo MFMA B-fragments (frag F=(t*2+kt)*4+nt, lane L: elem j =
// V[kt*32+(L>>4)*8+j][nt*16+(L&15)]; t=0 hi RTNE, t=1 residual).
__global__ void k_setupfv(float* __restrict__ ws) {
  int blk = blockIdx.x;
  if (blk < 32) {
    int t = blk * 256 + threadIdx.x;
    int b = t >> 6, d = t & 63;
    float s = 0;
    for (int m = 0; m < 64; ++m) s = fmaf(ws[WS_F + b*64+m], ws[WS_V + m*64+d], s);
    ws[WS_FZ + t] = s;
  } else {
    int idx = (blk - 32) * 256 + threadIdx.x;   // 0..1023
    int lane = idx & 63, F = idx >> 6;
    int t = F >> 3, kt = (F >> 2) & 1, nt = F & 3;
    int n = nt*16 + (lane & 15);
    int k0 = kt*32 + ((lane >> 4) & 3)*8;
    uint32_t out[4];
    for (int jj = 0; jj < 4; ++jj) {
      float v0 = ws[WS_V + (k0 + 2*jj    )*64 + n];
      float v1 = ws[WS_V + (k0 + 2*jj + 1)*64 + n];
      _Float16 h0, h1;
      if (t == 0) { h0 = (_Float16)v0; h1 = (_Float16)v1; }
      else {
        _Float16 a0 = (_Float16)v0, a1 = (_Float16)v1;
        h0 = (_Float16)(v0 - (float)a0);
        h1 = (_Float16)(v1 - (float)a1);
      }
      unsigned short u0 = __builtin_bit_cast(unsigned short, h0);
      unsigned short u1 = __builtin_bit_cast(unsigned short, h1);
      out[jj] = (uint32_t)u0 | ((uint32_t)u1 << 16);
    }
    uint32_t* dst = (uint32_t*)ws + WS_VF + idx*4;
    dst[0] = out[0]; dst[1] = out[1]; dst[2] = out[2]; dst[3] = out[3];
  }
}

// ---- k_main hot-loop macros ------------------------------------------------

#define DRAW(PC, IDX)                                                        \
  { uint32_t o0, o1;                                                         \
    threefry2x32(k0, k1, 0u, base + (IDX), o0, o1);                          \
    PC = 1.41421356f * erfinv_f(u_from_bits(o0 ^ o1)); }

#define SPLIT1(AH, AL, J, VV)                                                \
  { _Float16 hh = (_Float16)(VV); AH[J] = hh;                                \
    AL[J] = (_Float16)((VV) - (float)hh); }

#define DRAWSPLIT8(AH, AL, KB)                                               \
  { float dd;                                                                \
    DRAW(dd, (KB)+0) SPLIT1(AH, AL, 0, dd)                                   \
    DRAW(dd, (KB)+1) SPLIT1(AH, AL, 1, dd)                                   \
    DRAW(dd, (KB)+2) SPLIT1(AH, AL, 2, dd)                                   \
    DRAW(dd, (KB)+3) SPLIT1(AH, AL, 3, dd)                                   \
    DRAW(dd, (KB)+4) SPLIT1(AH, AL, 4, dd)                                   \
    DRAW(dd, (KB)+5) SPLIT1(AH, AL, 5, dd)                                   \
    DRAW(dd, (KB)+6) SPLIT1(AH, AL, 6, dd)                                   \
    DRAW(dd, (KB)+7) SPLIT1(AH, AL, 7, dd) }

#define FRAGB(T, KT, NT)                                                     \
  __builtin_bit_cast(half8_t, VF[(((T)*2+(KT))*4+(NT))*64 + lane])

#define ROT1(ZO, NT, AH0, AL0, AH1, AL1)                                     \
  { half8_t bh0 = FRAGB(0,0,NT), bh1 = FRAGB(0,1,NT);                        \
    half8_t bl0 = FRAGB(1,0,NT), bl1 = FRAGB(1,1,NT);                        \
    f4_t aa = {0.f, 0.f, 0.f, 0.f};                                          \
    aa = __builtin_amdgcn_mfma_f32_16x16x32_f16(AH0, bh0, aa, 0, 0, 0);      \
    aa = __builtin_amdgcn_mfma_f32_16x16x32_f16(AH1, bh1, aa, 0, 0, 0);      \
    aa = __builtin_amdgcn_mfma_f32_16x16x32_f16(AL0, bh0, aa, 0, 0, 0);      \
    aa = __builtin_amdgcn_mfma_f32_16x16x32_f16(AL1, bh1, aa, 0, 0, 0);      \
    aa = __builtin_amdgcn_mfma_f32_16x16x32_f16(AH0, bl0, aa, 0, 0, 0);      \
    aa = __builtin_amdgcn_mfma_f32_16x16x32_f16(AH1, bl1, aa, 0, 0, 0);      \
    ZO = aa; }

#define ROTATE4(O0, O1, O2, O3, AH0, AL0, AH1, AL1)                          \
  ROT1(O0, 0, AH0, AL0, AH1, AL1) ROT1(O1, 1, AH0, AL0, AH1, AL1)            \
  ROT1(O2, 2, AH0, AL0, AH1, AL1) ROT1(O3, 3, AH0, AL0, AH1, AL1)

#define LF1N(ZC, PC, LM, FC, DBL)                                            \
  { float gg = fmaf(bk, fmaf(-(LM), ZC, FC), -(ZC));                         \
    PC = fmaf(0.025f, gg, PC);                                               \
    if (DBL) PC = fmaf(0.025f, gg, PC);                                      \
    ZC = fmaf(0.05f, PC, ZC); }
#define LF4N(ZV, PV, LM, FV, DBL)                                            \
  LF1N(ZV.x, PV.x, LM, FV.x, DBL) LF1N(ZV.y, PV.y, LM, FV.y, DBL)            \
  LF1N(ZV.z, PV.z, LM, FV.z, DBL) LF1N(ZV.w, PV.w, LM, FV.w, DBL)
#define SUBSTEPN(DBL)                                                        \
  LF4N(z0, pz0, lmS0, fzv0, DBL) LF4N(z1, pz1, lmS1, fzv1, DBL)              \
  LF4N(z2, pz2, lmS2, fzv2, DBL) LF4N(z3, pz3, lmS3, fzv3, DBL)

#define W_EVALN(WOUT)                                                        \
  { f4_t s1 = fzv0*z0 + fzv1*z1 + fzv2*z2 + fzv3*z3;                         \
    f4_t s2 = (lmS0*z0)*z0 + (lmS1*z1)*z1 + (lmS2*z2)*z2 + (lmS3*z3)*z3;     \
    f4_t vv = s1 - 0.5f*s2;                                                  \
    float r0 = vv.x, r1 = vv.y, r2 = vv.z, r3 = vv.w;                        \
    r0 += __shfl_xor(r0, 1); r1 += __shfl_xor(r1, 1);                        \
    r2 += __shfl_xor(r2, 1); r3 += __shfl_xor(r3, 1);                        \
    r0 += __shfl_xor(r0, 2); r1 += __shfl_xor(r1, 2);                        \
    r2 += __shfl_xor(r2, 2); r3 += __shfl_xor(r3, 2);                        \
    r0 += __shfl_xor(r0, 4); r1 += __shfl_xor(r1, 4);                        \
    r2 += __shfl_xor(r2, 4); r3 += __shfl_xor(r3, 4);                        \
    r0 += __shfl_xor(r0, 8); r1 += __shfl_xor(r1, 8);                        \
    r2 += __shfl_xor(r2, 8); r3 += __shfl_xor(r3, 8);                        \
    float wsel = (cw == 0) ? r0 : ((cw == 1) ? r1 : ((cw == 2) ? r2 : r3));  \
    WOUT = wsel + wcs; }

// ---- main: MFMA rotation; wave = 16 trajs; 4 waves/block, 2048 blocks
__global__ __launch_bounds__(256, 2) void k_main(const float* __restrict__ qn,
                                                 const float* __restrict__ ws,
                                                 float* __restrict__ slw_out,
                                                 KParams P) {
  __shared__ uint4_t VF[1024];   // 16 KB: V f16 hi/lo B-fragments
  const int tid = threadIdx.x;
  {
    const uint4_t* src = (const uint4_t*)((const uint32_t*)ws + WS_VF);
    for (int i = tid; i < 1024; i += 256) VF[i] = src[i];
  }
  __syncthreads();

  const int lane = tid & 63;
  const int wv = tid >> 6;
  const int cw = lane & 15;              // MFMA col; also A-operand row m
  const int g4 = lane >> 4;              // quad id
  const int koff = g4 * 8;               // A-fragment k offset
  const int trajBase = blockIdx.x * 64 + wv * 16;
  const uint32_t base = (uint32_t)(trajBase + cw) * 64u;   // RNG row base

  const int b0 = (trajBase + g4*4 + 0) & 127;
  const int b1 = (trajBase + g4*4 + 1) & 127;
  const int b2 = (trajBase + g4*4 + 2) & 127;
  const int b3 = (trajBase + g4*4 + 3) & 127;
  f4_t fzv0, fzv1, fzv2, fzv3;
  fzv0.x = ws[WS_FZ + b0*64 + cw];      fzv0.y = ws[WS_FZ + b1*64 + cw];
  fzv0.z = ws[WS_FZ + b2*64 + cw];      fzv0.w = ws[WS_FZ + b3*64 + cw];
  fzv1.x = ws[WS_FZ + b0*64 + 16 + cw]; fzv1.y = ws[WS_FZ + b1*64 + 16 + cw];
  fzv1.z = ws[WS_FZ + b2*64 + 16 + cw]; fzv1.w = ws[WS_FZ + b3*64 + 16 + cw];
  fzv2.x = ws[WS_FZ + b0*64 + 32 + cw]; fzv2.y = ws[WS_FZ + b1*64 + 32 + cw];
  fzv2.z = ws[WS_FZ + b2*64 + 32 + cw]; fzv2.w = ws[WS_FZ + b3*64 + 32 + cw];
  fzv3.x = ws[WS_FZ + b0*64 + 48 + cw]; fzv3.y = ws[WS_FZ + b1*64 + 48 + cw];
  fzv3.z = ws[WS_FZ + b2*64 + 48 + cw]; fzv3.w = ws[WS_FZ + b3*64 + 48 + cw];
  const float lmS0 = ws[WS_LAM + cw];
  const float lmS1 = ws[WS_LAM + 16 + cw];
  const float lmS2 = ws[WS_LAM + 32 + cw];
  const float lmS3 = ws[WS_LAM + 48 + cw];
  const float wcs = ws[WS_WC + ((trajBase + g4*4 + (cw & 3)) & 127)];

  f4_t z0, z1, z2, z3, pz0, pz1, pz2, pz3;
  float slw = 0.0f;

  // j = 0: z0 = qn . V  (qn read at A-fragment positions; f16 3-term split)
  {
    const float* qp = qn + (size_t)base;
    f4_t qa = *(const f4_t*)(qp + koff);
    f4_t qb = *(const f4_t*)(qp + koff + 4);
    f4_t qc = *(const f4_t*)(qp + 32 + koff);
    f4_t qd = *(const f4_t*)(qp + 32 + koff + 4);
    half8_t ah0, al0, ah1, al1;
    SPLIT1(ah0, al0, 0, qa.x) SPLIT1(ah0, al0, 1, qa.y)
    SPLIT1(ah0, al0, 2, qa.z) SPLIT1(ah0, al0, 3, qa.w)
    SPLIT1(ah0, al0, 4, qb.x) SPLIT1(ah0, al0, 5, qb.y)
    SPLIT1(ah0, al0, 6, qb.z) SPLIT1(ah0, al0, 7, qb.w)
    SPLIT1(ah1, al1, 0, qc.x) SPLIT1(ah1, al1, 1, qc.y)
    SPLIT1(ah1, al1, 2, qc.z) SPLIT1(ah1, al1, 3, qc.w)
    SPLIT1(ah1, al1, 4, qd.x) SPLIT1(ah1, al1, 5, qd.y)
    SPLIT1(ah1, al1, 6, qd.z) SPLIT1(ah1, al1, 7, qd.w)
    ROTATE4(z0, z1, z2, z3, ah0, al0, ah1, al1)
  }
  {
    float w0;
    W_EVALN(w0);
    slw = fmaf(P.dbeta[0], w0, slw);
  }

  for (int j = 1; j <= 16; ++j) {
    const float bk = P.beta[j];
    const uint32_t k0 = P.fk0[j-1], k1 = P.fk1[j-1];
    half8_t ah0, al0, ah1, al1;
    DRAWSPLIT8(ah0, al0, koff)
    DRAWSPLIT8(ah1, al1, 32 + koff)
    ROTATE4(pz0, pz1, pz2, pz3, ah0, al0, ah1, al1)   // pz = p . V
    SUBSTEPN(false)
    SUBSTEPN(true)
    SUBSTEPN(true)
    float wj;
    W_EVALN(wj);
    slw = fmaf(P.dbeta[j], wj, slw);
  }
  if (cw < 4) slw_out[trajBase + g4*4 + cw] = slw;
}

// ---- logsumexp over n per batch column b
__global__ void k_reduce(const float* __restrict__ slw, float* __restrict__ out) {
  __shared__ float red[256];
  int b = blockIdx.x, t = threadIdx.x;
  float v0 = slw[t*128 + b];
  float v1 = slw[(t+256)*128 + b];
  float v2 = slw[(t+512)*128 + b];
  float v3 = slw[(t+768)*128 + b];
  float m = fmaxf(fmaxf(v0, v1), fmaxf(v2, v3));
  red[t] = m; __syncthreads();
  for (int s = 128; s > 0; s >>= 1) {
    if (t < s) red[t] = fmaxf(red[t], red[t+s]);
    __syncthreads();
  }
  m = red[0]; __syncthreads();
  float sum = expf(v0 - m) + expf(v1 - m) + expf(v2 - m) + expf(v3 - m);
  red[t] = sum; __syncthreads();
  for (int s = 128; s > 0; s >>= 1) {
    if (t < s) red[t] += red[t+s];
    __syncthreads();
  }
  if (t == 0) out[b] = m + logf(red[0]) - 6.93147180559945309f;  // - log(1024)
}

extern "C" void kernel_launch(void* const* d_in, const int* in_sizes, int n_in,
                              void* d_out, int out_size, void* d_ws, size_t ws_size,
                              hipStream_t stream) {
  const float* x    = (const float*)d_in[0];
  const float* Wenc = (const float*)d_in[1];
  const float* Wdec = (const float*)d_in[2];
  const float* qn   = (const float*)d_in[3];
  // d_in[4] (p_noise) is dead: momentum fully resampled every anneal step.
  float* ws  = (float*)d_ws;
  float* out = (float*)d_out;
  if (ws_size < (size_t)WS_TOTAL * sizeof(float)) return;

  KParams P;
  double bb[18];
  for (int i = 0; i < 18; ++i) {
    double tt = (double)i / 17.0;
    bb[i] = 1.0 / (1.0 + exp(-(8.0 * tt - 4.0)));
  }
  for (int i = 0; i < 18; ++i) P.beta[i] = (float)((bb[i] - bb[0]) / (bb[17] - bb[0]));
  for (int j = 0; j <= 16; ++j) P.dbeta[j] = P.beta[j+1] - P.beta[j];
  for (int k = 1; k <= 16; ++k) {
    uint32_t a, c;
    threefry2x32(0u, 42u, 0u, (uint32_t)k, a, c);  // fold_in(key(42), k)
    P.fk0[k-1] = a; P.fk1[k-1] = c;
  }

  hipLaunchKernelGGL(k_setup1, dim3(81), dim3(256), 0, stream, x, Wenc, Wdec, ws);
  hipLaunchKernelGGL(k_eig, dim3(1), dim3(1024), 0, stream, ws);
  hipLaunchKernelGGL(k_setup2, dim3(32), dim3(256), 0, stream, ws);
  hipLaunchKernelGGL(k_setup3, dim3(1), dim3(128), 0, stream, ws);
  hipLaunchKernelGGL(k_setupfv, dim3(36), dim3(256), 0, stream, ws);
  hipLaunchKernelGGL(k_main, dim3(2048), dim3(256), 0, stream, qn, ws, ws + WS_SLW, P);
  hipLaunchKernelGGL(k_reduce, dim3(128), dim3(256), 0, stream, ws + WS_SLW, out);
}